// Round 5
// baseline (9489.156 us; speedup 1.0000x reference)
//
#include <hip/hip_runtime.h>
#include <hip/hip_bf16.h>
#include <math.h>

// ---- JAX threefry RNG: partitionable, bits = o0 ^ o1 [VERIFIED round 2] ----

typedef short short8 __attribute__((ext_vector_type(8)));
typedef float f32x4 __attribute__((ext_vector_type(4)));

__host__ __device__ inline void tf2x32(unsigned k0, unsigned k1,
                                       unsigned x0, unsigned x1,
                                       unsigned& o0, unsigned& o1) {
  unsigned ks2 = k0 ^ k1 ^ 0x1BD11BDAu;
#define TF_R(x, r) x0 += x1; x1 = ((x1 << (r)) | (x1 >> (32 - (r)))); x1 ^= x0;
  x0 += k0; x1 += k1;
  TF_R(x1,13) TF_R(x1,15) TF_R(x1,26) TF_R(x1,6)
  x0 += k1; x1 += ks2 + 1u;
  TF_R(x1,17) TF_R(x1,29) TF_R(x1,16) TF_R(x1,24)
  x0 += ks2; x1 += k0 + 2u;
  TF_R(x1,13) TF_R(x1,15) TF_R(x1,26) TF_R(x1,6)
  x0 += k0; x1 += k1 + 3u;
  TF_R(x1,17) TF_R(x1,29) TF_R(x1,16) TF_R(x1,24)
  x0 += k1; x1 += ks2 + 4u;
  TF_R(x1,13) TF_R(x1,15) TF_R(x1,26) TF_R(x1,6)
  x0 += ks2; x1 += k0 + 5u;
#undef TF_R
  o0 = x0; o1 = x1;
}

__global__ void k_idx(int* __restrict__ idx, unsigned k2a, unsigned k2b,
                      int n, int mask) {
  int j = blockIdx.x * 256 + threadIdx.x;
  if (j >= n) return;
  unsigned o0, o1;
  tf2x32(k2a, k2b, 0u, (unsigned)j, o0, o1);
  idx[j] = (int)((o0 ^ o1) & (unsigned)mask);
}

// positional-encoding table, fp64 math (matches numpy float64 promotion path)
__global__ void k_pe(float* __restrict__ pe) {
  int t = blockIdx.x * 256 + threadIdx.x;   // over 4096*512
  int l = t >> 9, d = t & 511;
  double div = exp((double)(d & ~1) * (-9.210340371976184 / 512.0));
  double ang = (double)l * div;
  pe[t] = (float)((d & 1) ? cos(ang) : sin(ang));
}

// h = x @ emb_w^T + emb_b + pe   (K=64, 16 rows per block)
__global__ __launch_bounds__(256) void k_embed(const float* __restrict__ x,
    const float* __restrict__ W, const float* __restrict__ eb,
    const float* __restrict__ pe, float* __restrict__ out) {
  __shared__ __align__(16) float xs[16][64];
  int r0 = blockIdx.x * 16;
  int t = threadIdx.x;
  ((float4*)&xs[0][0])[t] = ((const float4*)(x + (size_t)r0 * 64))[t];
  __syncthreads();
  int d0 = t, d1 = t + 256;
  float acc0[16], acc1[16];
#pragma unroll
  for (int r = 0; r < 16; r++) { acc0[r] = 0.f; acc1[r] = 0.f; }
  for (int k = 0; k < 64; k++) {
    float w0 = W[d0 * 64 + k], w1 = W[d1 * 64 + k];
#pragma unroll
    for (int r = 0; r < 16; r++) {
      float xv = xs[r][k];
      acc0[r] = fmaf(xv, w0, acc0[r]);
      acc1[r] = fmaf(xv, w1, acc1[r]);
    }
  }
  float eb0 = eb[d0], eb1 = eb[d1];
#pragma unroll
  for (int r = 0; r < 16; r++) {
    int row = r0 + r;
    int l = row & 4095;
    out[(size_t)row * 512 + d0] = acc0[r] + eb0 + pe[(size_t)l * 512 + d0];
    out[(size_t)row * 512 + d1] = acc1[r] + eb1 + pe[(size_t)l * 512 + d1];
  }
}

// per-(b,h,d) mean over L (fp64)
__global__ __launch_bounds__(256) void k_colmean(const float* __restrict__ X,
    float* __restrict__ meanq, int L) {
  int bh = blockIdx.x, b = bh >> 3, h = bh & 7;
  int w = threadIdx.x >> 6, d = threadIdx.x & 63;
  const float* base = X + (size_t)b * L * 512 + h * 64 + d;
  double s = 0.0;
  for (int l = w; l < L; l += 4) s += (double)base[(size_t)l * 512];
  __shared__ double red[4][64];
  red[w][d] = s;
  __syncthreads();
  if (w == 0)
    meanq[bh * 64 + d] = (float)((red[0][d] + red[1][d] + red[2][d] + red[3][d]) / (double)L);
}

// M[b,h,l] = max_s dot(q_l, q_idx[l,s]) - sum_s(...)/L  (fp64, lane = sample)
__global__ __launch_bounds__(256) void k_M(const float* __restrict__ X,
    const int* __restrict__ idx, float* __restrict__ Mout, int L, int u) {
  int w = threadIdx.x >> 6, lane = threadIdx.x & 63;
  int gl = blockIdx.x * 4 + w;
  int l = gl % L, bh = gl / L, b = bh >> 3, h = bh & 7;
  const float* Xbh = X + (size_t)b * L * 512 + h * 64;
  __shared__ float qs[4][64];
  qs[w][lane] = Xbh[(size_t)l * 512 + lane];
  __syncthreads();
  bool act = lane < u;
  double dot = 0.0;
  if (act) {
    int kidx = idx[l * u + lane];
    const float4* kp = (const float4*)(Xbh + (size_t)kidx * 512);
#pragma unroll
    for (int dq = 0; dq < 16; dq++) {
      float4 kv = kp[dq];
      dot += (double)qs[w][dq * 4 + 0] * (double)kv.x;
      dot += (double)qs[w][dq * 4 + 1] * (double)kv.y;
      dot += (double)qs[w][dq * 4 + 2] * (double)kv.z;
      dot += (double)qs[w][dq * 4 + 3] * (double)kv.w;
    }
  }
  double mv = act ? dot : -1e300;
  double sv = act ? dot : 0.0;
  for (int off = 32; off; off >>= 1) {
    mv = fmax(mv, __shfl_xor(mv, off));
    sv += __shfl_xor(sv, off);
  }
  if (lane == 0) Mout[(size_t)bh * L + l] = (float)(mv - sv / (double)L);
}

// iterative top-u argmax per (b,h); tie -> smaller index (matches lax.top_k)
__global__ __launch_bounds__(256) void k_topk(const float* __restrict__ M,
    int* __restrict__ top, int L, int u) {
  __shared__ float mv[4096];
  __shared__ float rv[256];
  __shared__ int ri[256];
  int bh = blockIdx.x, t = threadIdx.x;
  const float* Mr = M + (size_t)bh * L;
  for (int k = t; k < L; k += 256) mv[k] = Mr[k];
  __syncthreads();
  for (int it = 0; it < u; it++) {
    float bv = -1e30f; int bi = 0x7fffffff;
    for (int k = t; k < L; k += 256) {
      float v = mv[k];
      if (v > bv) { bv = v; bi = k; }
    }
    rv[t] = bv; ri[t] = bi;
    __syncthreads();
    for (int off = 128; off; off >>= 1) {
      if (t < off) {
        float v2 = rv[t + off]; int i2 = ri[t + off];
        if (v2 > rv[t] || (v2 == rv[t] && i2 < ri[t])) { rv[t] = v2; ri[t] = i2; }
      }
      __syncthreads();
    }
    if (t == 0) { top[bh * u + it] = ri[0]; mv[ri[0]] = -1e30f; }
    __syncthreads();
  }
}

// ATT <- broadcast mean
__global__ void k_fill(float* __restrict__ A, const float* __restrict__ meanq, int L) {
  size_t t = (size_t)blockIdx.x * 256 + threadIdx.x;
  size_t e = t * 4;
  int dm = (int)(e & 511);
  int b = (int)((e >> 9) / (size_t)L);
  *(float4*)(A + e) = *(const float4*)(meanq + b * 512 + dm);
}

// S[bh,ur,k] = scale * dot(q_red[ur], q_k) for 64-k tile per block
__global__ __launch_bounds__(256) void k_scores(const float* __restrict__ X,
    const int* __restrict__ top, float* __restrict__ S, int L, int u) {
  __shared__ __align__(16) float ktT[64][68];
  __shared__ __align__(16) float qred[48][64];
  int bh = blockIdx.y, b = bh >> 3, h = bh & 7;
  int k0 = blockIdx.x * 64;
  int t = threadIdx.x;
  const float* Xbh = X + (size_t)b * L * 512 + h * 64;
#pragma unroll
  for (int it = 0; it < 4; it++) {
    int lin = t + it * 256;                // (kk, fi) over 64x16
    int kk = lin >> 4, fi = lin & 15;
    float4 v = *(const float4*)(Xbh + (size_t)(k0 + kk) * 512 + fi * 4);
    ktT[fi * 4 + 0][kk] = v.x; ktT[fi * 4 + 1][kk] = v.y;
    ktT[fi * 4 + 2][kk] = v.z; ktT[fi * 4 + 3][kk] = v.w;
  }
#pragma unroll
  for (int it = 0; it < 3; it++) {
    int lin = t + it * 256;                // (ur, fi) over 48x16
    int ur = lin >> 4, fi = lin & 15;
    if (ur < u) {
      int row = top[bh * u + ur];
      *(float4*)(&qred[ur][fi * 4]) = *(const float4*)(Xbh + (size_t)row * 512 + fi * 4);
    } else if (ur < 48) {
      *(float4*)(&qred[ur][fi * 4]) = make_float4(0.f, 0.f, 0.f, 0.f);
    }
  }
  __syncthreads();
  int xq = t & 15, y = t >> 4;
  float acc[3][4];
#pragma unroll
  for (int j = 0; j < 3; j++)
#pragma unroll
    for (int e = 0; e < 4; e++) acc[j][e] = 0.f;
  for (int d = 0; d < 64; d++) {
    float4 kv = *(const float4*)(&ktT[d][xq * 4]);
#pragma unroll
    for (int j = 0; j < 3; j++) {
      float qv = qred[y * 3 + j][d];
      acc[j][0] = fmaf(qv, kv.x, acc[j][0]);
      acc[j][1] = fmaf(qv, kv.y, acc[j][1]);
      acc[j][2] = fmaf(qv, kv.z, acc[j][2]);
      acc[j][3] = fmaf(qv, kv.w, acc[j][3]);
    }
  }
#pragma unroll
  for (int j = 0; j < 3; j++) {
    int ur = y * 3 + j;
    if (ur < u) {
      float4 o = make_float4(acc[j][0] * 0.125f, acc[j][1] * 0.125f,
                             acc[j][2] * 0.125f, acc[j][3] * 0.125f);
      *(float4*)(S + ((size_t)(bh * u + ur)) * L + k0 + xq * 4) = o;
    }
  }
}

// softmax over k + ctx_top row, written straight into ATT at top position.
// PV phase: 8-way unrolled independent fp64 partials (breaks the serial
// dep-chain that made round-4's version latency-bound at 27% VALUBusy).
__global__ __launch_bounds__(256) void k_ctx(const float* __restrict__ X,
    const float* __restrict__ S, const int* __restrict__ top,
    float* __restrict__ A, int L, int u) {
  int ur = blockIdx.x, bh = blockIdx.y, b = bh >> 3, h = bh & 7;
  const float* Srow = S + ((size_t)(bh * u + ur)) * L;
  int t = threadIdx.x;
  __shared__ float wtab[4096];
  __shared__ float rm[256];
  __shared__ double rs[256];
  __shared__ double red[4][64];
  float m = -1e30f;
  for (int k = t; k < L; k += 256) m = fmaxf(m, Srow[k]);
  rm[t] = m; __syncthreads();
  for (int off = 128; off; off >>= 1) {
    if (t < off) rm[t] = fmaxf(rm[t], rm[t + off]);
    __syncthreads();
  }
  float mx = rm[0];
  double s = 0.0;
  for (int k = t; k < L; k += 256) { float e = expf(Srow[k] - mx); wtab[k] = e; s += (double)e; }
  rs[t] = s; __syncthreads();
  for (int off = 128; off; off >>= 1) {
    if (t < off) rs[t] += rs[t + off];
    __syncthreads();
  }
  double inv = 1.0 / rs[0];
  int w = t >> 6, lane = t & 63;
  const float* Xc = X + (size_t)b * L * 512 + h * 64 + lane;
  double a0 = 0.0, a1 = 0.0, a2 = 0.0, a3 = 0.0;
  double a4 = 0.0, a5 = 0.0, a6 = 0.0, a7 = 0.0;
  for (int j = w; j < L; j += 32) {
    float x0 = Xc[(size_t)j * 512];
    float x1 = Xc[(size_t)(j + 4) * 512];
    float x2 = Xc[(size_t)(j + 8) * 512];
    float x3 = Xc[(size_t)(j + 12) * 512];
    float x4 = Xc[(size_t)(j + 16) * 512];
    float x5 = Xc[(size_t)(j + 20) * 512];
    float x6 = Xc[(size_t)(j + 24) * 512];
    float x7 = Xc[(size_t)(j + 28) * 512];
    float p0 = wtab[j],      p1 = wtab[j + 4],  p2 = wtab[j + 8],  p3 = wtab[j + 12];
    float p4 = wtab[j + 16], p5 = wtab[j + 20], p6 = wtab[j + 24], p7 = wtab[j + 28];
    a0 += (double)p0 * (double)x0; a1 += (double)p1 * (double)x1;
    a2 += (double)p2 * (double)x2; a3 += (double)p3 * (double)x3;
    a4 += (double)p4 * (double)x4; a5 += (double)p5 * (double)x5;
    a6 += (double)p6 * (double)x6; a7 += (double)p7 * (double)x7;
  }
  red[w][lane] = ((a0 + a1) + (a2 + a3)) + ((a4 + a5) + (a6 + a7));
  __syncthreads();
  if (w == 0) {
    double tot = (red[0][lane] + red[1][lane] + red[2][lane] + red[3][lane]) * inv;
    int row = top[bh * u + ur];
    A[((size_t)b * L + row) * 512 + h * 64 + lane] = (float)tot;
  }
}

// X <- LN(X + A) * gs + gb, in place; one wave per 512-wide row
__global__ __launch_bounds__(256) void k_ln1(float* __restrict__ X,
    const float* __restrict__ A, const float* __restrict__ gs,
    const float* __restrict__ gb) {
  int w = threadIdx.x >> 6, lane = threadIdx.x & 63;
  int row = blockIdx.x * 4 + w;
  float* xr = X + (size_t)row * 512;
  const float* ar = A + (size_t)row * 512;
  float v[8]; double s = 0.0, s2 = 0.0;
#pragma unroll
  for (int i = 0; i < 8; i++) {
    float val = xr[lane + i * 64] + ar[lane + i * 64];
    v[i] = val; s += (double)val; s2 += (double)val * (double)val;
  }
  for (int off = 32; off; off >>= 1) { s += __shfl_xor(s, off); s2 += __shfl_xor(s2, off); }
  double mu = s * (1.0 / 512.0);
  double var = s2 * (1.0 / 512.0) - mu * mu;
  float rsd = (float)(1.0 / sqrt(var + 1e-5));
  float muf = (float)mu;
#pragma unroll
  for (int i = 0; i < 8; i++) {
    int d = lane + i * 64;
    xr[d] = (v[i] - muf) * rsd * gs[d] + gb[d];
  }
}

// out <- LN(X + Y2); optional pair-pool (distil); one wave per output row
__global__ __launch_bounds__(256) void k_ln2(const float* __restrict__ X,
    const float* __restrict__ Y2, const float* __restrict__ gs,
    const float* __restrict__ gb, float* __restrict__ out, int pool) {
  int w = threadIdx.x >> 6, lane = threadIdx.x & 63;
  int orow = blockIdx.x * 4 + w;
  float o[8] = {0.f,0.f,0.f,0.f,0.f,0.f,0.f,0.f};
  int reps = pool ? 2 : 1;
  for (int p = 0; p < reps; p++) {
    int row = pool ? (orow * 2 + p) : orow;
    const float* xr = X + (size_t)row * 512;
    const float* yr = Y2 + (size_t)row * 512;
    float v[8]; double s = 0.0, s2 = 0.0;
#pragma unroll
    for (int i = 0; i < 8; i++) {
      float val = xr[lane + i * 64] + yr[lane + i * 64];
      v[i] = val; s += (double)val; s2 += (double)val * (double)val;
    }
    for (int off = 32; off; off >>= 1) { s += __shfl_xor(s, off); s2 += __shfl_xor(s2, off); }
    double mu = s * (1.0 / 512.0);
    double var = s2 * (1.0 / 512.0) - mu * mu;
    float rsd = (float)(1.0 / sqrt(var + 1e-5));
    float muf = (float)mu;
#pragma unroll
    for (int i = 0; i < 8; i++)
      o[i] += (v[i] - muf) * rsd * gs[lane + i * 64] + gb[lane + i * 64];
  }
  float sc = pool ? 0.5f : 1.0f;
#pragma unroll
  for (int i = 0; i < 8; i++)
    out[(size_t)orow * 512 + lane + i * 64] = o[i] * sc;
}

// ---------------- bf16x3 MFMA GEMM (v3: LDS-free) ----------------
// Round-4 was LDS-pipe bound (144KB LDS traffic vs 460clk MFMA per kt).
// v3 loads fragments DIRECTLY per-lane from global: A (fp32) split to
// bf16x3 in-register; B (weights) from pre-split global bf16 planes.
// No LDS, no barriers in the K-loop. Same 6-term MFMA order as round 4
// -> bitwise-identical output.
// Fragment layout (16x16x32): lane holds row r=lane&15, k=(lane>>4)*8+j.

__device__ inline unsigned bsplit(float x, float y, float& rx, float& ry) {
  union { __hip_bfloat162 h; unsigned u; } c;
  c.h = __float22bfloat162_rn(make_float2(x, y));
  rx = x - __uint_as_float(c.u << 16);
  ry = y - __uint_as_float(c.u & 0xffff0000u);
  return c.u;
}

union U4S8 { uint4 u; short8 s; };

__device__ inline void split3_reg(float4 v0, float4 v1,
                                  short8& ho, short8& mo, short8& lo) {
  U4S8 H, M, L; float r[8], r2[8]; float d0, d1;
  H.u.x = bsplit(v0.x, v0.y, r[0], r[1]);
  H.u.y = bsplit(v0.z, v0.w, r[2], r[3]);
  H.u.z = bsplit(v1.x, v1.y, r[4], r[5]);
  H.u.w = bsplit(v1.z, v1.w, r[6], r[7]);
  M.u.x = bsplit(r[0], r[1], r2[0], r2[1]);
  M.u.y = bsplit(r[2], r[3], r2[2], r2[3]);
  M.u.z = bsplit(r[4], r[5], r2[4], r2[5]);
  M.u.w = bsplit(r[6], r[7], r2[6], r2[7]);
  L.u.x = bsplit(r2[0], r2[1], d0, d1);
  L.u.y = bsplit(r2[2], r2[3], d0, d1);
  L.u.z = bsplit(r2[4], r2[5], d0, d1);
  L.u.w = bsplit(r2[6], r2[7], d0, d1);
  ho = H.s; mo = M.s; lo = L.s;
}

// W[N][K] fp32 -> 3 contiguous bf16 planes [N][K] (hi, mid, lo)
__global__ void k_splitW(const float* __restrict__ W, unsigned* __restrict__ out,
                         int total2) {
  int j = blockIdx.x * 256 + threadIdx.x;   // pair index
  if (j >= total2) return;
  float2 v = ((const float2*)W)[j];
  float r0, r1, s0, s1;
  unsigned h = bsplit(v.x, v.y, r0, r1);
  unsigned m = bsplit(r0, r1, s0, s1);
  unsigned l = bsplit(s0, s1, r0, r1);
  out[j] = h; out[total2 + j] = m; out[2 * total2 + j] = l;
}

template <int GELU>
__global__ void k_gemm(const float* __restrict__ A, const char* __restrict__ B3,
    const float* __restrict__ bias, float* __restrict__ C, int N, int K) {
  const int t = threadIdx.x;
  const int m0 = blockIdx.y * 128, n0 = blockIdx.x * 128;
  const int w = t >> 6, lane = t & 63;
  const int wm = (w >> 1) * 4, wn = (w & 1) * 4;   // 16-tile indices
  const int rit = lane & 15, quad = lane >> 4, qc = quad * 8;
  const size_t pstride = (size_t)N * K * 2;        // bytes per plane
  const float* Aptr[4];
  const char* Bptr[4];
#pragma unroll
  for (int mi = 0; mi < 4; mi++)
    Aptr[mi] = A + (size_t)(m0 + (wm + mi) * 16 + rit) * K + qc;
#pragma unroll
  for (int ni = 0; ni < 4; ni++)
    Bptr[ni] = B3 + ((size_t)(n0 + (wn + ni) * 16 + rit) * K + qc) * 2;
  f32x4 acc[4][4];
#pragma unroll
  for (int i = 0; i < 4; i++)
#pragma unroll
    for (int j = 0; j < 4; j++) acc[i][j] = (f32x4){0.f, 0.f, 0.f, 0.f};
  // prefetch A for kt=0
  float4 pa0[4], pa1[4];
#pragma unroll
  for (int mi = 0; mi < 4; mi++) {
    pa0[mi] = *(const float4*)(Aptr[mi]);
    pa1[mi] = *(const float4*)(Aptr[mi] + 4);
  }
  const int KT = K >> 5;
  for (int kt = 0; kt < KT; kt++) {
    short8 af[3][4];
#pragma unroll
    for (int mi = 0; mi < 4; mi++)
      split3_reg(pa0[mi], pa1[mi], af[0][mi], af[1][mi], af[2][mi]);
    if (kt + 1 < KT) {
      const int ko = (kt + 1) * 32;
#pragma unroll
      for (int mi = 0; mi < 4; mi++) {
        pa0[mi] = *(const float4*)(Aptr[mi] + ko);
        pa1[mi] = *(const float4*)(Aptr[mi] + ko + 4);
      }
    }
    const size_t bo = (size_t)kt * 64;   // byte offset within a plane row
    short8 bh = *(const short8*)(Bptr[0] + bo);
    short8 bm = *(const short8*)(Bptr[0] + pstride + bo);
    short8 bl = *(const short8*)(Bptr[0] + 2 * pstride + bo);
#pragma unroll
    for (int ni = 0; ni < 4; ni++) {
      short8 cbh = bh, cbm = bm, cbl = bl;
      if (ni + 1 < 4) {
        bh = *(const short8*)(Bptr[ni + 1] + bo);
        bm = *(const short8*)(Bptr[ni + 1] + pstride + bo);
        bl = *(const short8*)(Bptr[ni + 1] + 2 * pstride + bo);
      }
#pragma unroll
      for (int mi = 0; mi < 4; mi++) {
        f32x4 c = acc[mi][ni];
        c = __builtin_amdgcn_mfma_f32_16x16x32_bf16(af[0][mi], cbh, c, 0, 0, 0);
        c = __builtin_amdgcn_mfma_f32_16x16x32_bf16(af[0][mi], cbm, c, 0, 0, 0);
        c = __builtin_amdgcn_mfma_f32_16x16x32_bf16(af[1][mi], cbh, c, 0, 0, 0);
        c = __builtin_amdgcn_mfma_f32_16x16x32_bf16(af[1][mi], cbm, c, 0, 0, 0);
        c = __builtin_amdgcn_mfma_f32_16x16x32_bf16(af[0][mi], cbl, c, 0, 0, 0);
        c = __builtin_amdgcn_mfma_f32_16x16x32_bf16(af[2][mi], cbh, c, 0, 0, 0);
        acc[mi][ni] = c;
      }
    }
  }
  // epilogue: C/D layout col=lane&15, row=quad*4+e
#pragma unroll
  for (int mi = 0; mi < 4; mi++) {
    const int gr0 = m0 + (wm + mi) * 16 + quad * 4;
#pragma unroll
    for (int ni = 0; ni < 4; ni++) {
      const int gc = n0 + (wn + ni) * 16 + rit;
      const float bia = bias[gc];
#pragma unroll
      for (int e = 0; e < 4; e++) {
        float v = acc[mi][ni][e] + bia;
        if (GELU) v = 0.5f * v * (1.0f + erff(v * 0.7071067811865476f));
        C[(size_t)(gr0 + e) * N + gc] = v;
      }
    }
  }
}

extern "C" void kernel_launch(void* const* d_in, const int* in_sizes, int n_in,
                              void* d_out, int out_size, void* d_ws, size_t ws_size,
                              hipStream_t stream) {
  const float* x     = (const float*)d_in[0];
  const float* emb_w = (const float*)d_in[1];
  const float* emb_b = (const float*)d_in[2];
  const float* ln1_s = (const float*)d_in[3];
  const float* ln1_b = (const float*)d_in[4];
  const float* w1    = (const float*)d_in[5];
  const float* b1    = (const float*)d_in[6];
  const float* w2    = (const float*)d_in[7];
  const float* b2    = (const float*)d_in[8];
  const float* ln2_s = (const float*)d_in[9];
  const float* ln2_b = (const float*)d_in[10];
  const float* out_w = (const float*)d_in[11];
  const float* out_b = (const float*)d_in[12];
  float* outp = (float*)d_out;

  // workspace layout (<= 209 MiB; verified ws >= 212 MiB in round 2)
  char* ws = (char*)d_ws;
  if (ws_size < (212ULL << 20)) return;  // insufficient scratch -> fail loudly
  float*    PE   = (float*)(ws);                    // 8 MiB, dead after embed
  unsigned* W1S  = (unsigned*)(ws);                 // 6 MiB, overlays dead PE
  float* BUF[3]  = { (float*)(ws + (8ULL << 20)),
                     (float*)(ws + (72ULL << 20)),
                     (float*)(ws + (136ULL << 20)) };  // 3 x 64 MiB
  unsigned* W2S  = (unsigned*)(ws + (200ULL << 20));   // 6 MiB
  float* MB      = (float*)(ws + (206ULL << 20));      // 1 MiB
  int*   IDX     = (int*)  (ws + (207ULL << 20));      // <1 MiB
  int*   TOP     = (int*)  (ws + (208ULL << 20));
  float* MEANQ   = (float*)(ws + (208ULL << 20) + (64 << 10));

  k_pe<<<4096 * 512 / 256, 256, 0, stream>>>(PE);
  k_embed<<<(8 * 4096) / 16, 256, 0, stream>>>(x, emb_w, emb_b, PE, BUF[0]);

  const int Ls[3] = {4096, 2048, 1024};
  const int us[3] = {45, 40, 35};
  int xi = 0, ai = 1, yi = 2;
  for (int layer = 0; layer < 3; layer++) {
    const int L = Ls[layer], u = us[layer];
    float* X = BUF[xi]; float* A = BUF[ai]; float* Y = BUF[yi];

    // pre-split this layer's weights into bf16x3 planes (PE is dead by now)
    k_splitW<<<(2048 * 512 / 2 + 255) / 256, 256, 0, stream>>>(
        w1 + (size_t)layer * 2048 * 512, W1S, 2048 * 512 / 2);
    k_splitW<<<(512 * 2048 / 2 + 255) / 256, 256, 0, stream>>>(
        w2 + (size_t)layer * 512 * 2048, W2S, 512 * 2048 / 2);

    // layer key = fold_in(key(42), layer); k2 = second split key
    unsigned Ka, Kb, k2a, k2b;
    tf2x32(0u, 42u, 0u, (unsigned)layer, Ka, Kb);
    tf2x32(Ka, Kb, 0u, 1u, k2a, k2b);
    const int n = L * u;
    k_idx<<<(n + 255) / 256, 256, 0, stream>>>(IDX, k2a, k2b, n, L - 1);
    k_colmean<<<64, 256, 0, stream>>>(X, MEANQ, L);
    k_M<<<64 * L / 4, 256, 0, stream>>>(X, IDX, MB, L, u);
    k_topk<<<64, 256, 0, stream>>>(MB, TOP, L, u);
    k_fill<<<8 * L / 2, 256, 0, stream>>>(A, MEANQ, L);
    k_scores<<<dim3(L / 64, 64), 256, 0, stream>>>(X, TOP, Y, L, u);
    k_ctx<<<dim3(u, 64), 256, 0, stream>>>(X, Y, TOP, A, L, u);
    k_ln1<<<8 * L / 4, 256, 0, stream>>>(X, A, ln1_s + layer * 512, ln1_b + layer * 512);

    const int chunks = (8 * L) / 8192;
    for (int c = 0; c < chunks; c++) {
      k_gemm<1><<<dim3(16, 64), 256, 0, stream>>>(
          X + (size_t)c * 8192 * 512, (const char*)W1S,
          b1 + layer * 2048, Y, 2048, 512);
      k_gemm<0><<<dim3(4, 64), 256, 0, stream>>>(
          Y, (const char*)W2S, b2 + layer * 512,
          A + (size_t)c * 8192 * 512, 512, 2048);
    }
    if (layer < 2)
      k_ln2<<<8 * (L / 2) / 4, 256, 0, stream>>>(X, A, ln2_s + layer * 512,
                                                 ln2_b + layer * 512, Y, 1);
    else
      k_ln2<<<8 * L / 4, 256, 0, stream>>>(X, A, ln2_s + layer * 512,
                                           ln2_b + layer * 512, Y, 0);
    int tswap = xi; xi = yi; yi = ai; ai = tswap;  // next X = Y
  }
  // final projection: (8*1024, 512) @ out_w^T + out_b
  k_splitW<<<(512 * 512 / 2 + 255) / 256, 256, 0, stream>>>(
      out_w, W1S, 512 * 512 / 2);
  k_gemm<0><<<dim3(4, 64), 256, 0, stream>>>(BUF[xi], (const char*)W1S,
                                             out_b, outp, 512, 512);
}

// Round 6
// 4325.839 us; speedup vs baseline: 2.1936x; 2.1936x over previous
//
#include <hip/hip_runtime.h>
#include <hip/hip_bf16.h>
#include <math.h>

// ---- JAX threefry RNG: partitionable, bits = o0 ^ o1 [VERIFIED round 2] ----

typedef short short8 __attribute__((ext_vector_type(8)));
typedef float f32x4 __attribute__((ext_vector_type(4)));
typedef unsigned int uint;

__host__ __device__ inline void tf2x32(unsigned k0, unsigned k1,
                                       unsigned x0, unsigned x1,
                                       unsigned& o0, unsigned& o1) {
  unsigned ks2 = k0 ^ k1 ^ 0x1BD11BDAu;
#define TF_R(x, r) x0 += x1; x1 = ((x1 << (r)) | (x1 >> (32 - (r)))); x1 ^= x0;
  x0 += k0; x1 += k1;
  TF_R(x1,13) TF_R(x1,15) TF_R(x1,26) TF_R(x1,6)
  x0 += k1; x1 += ks2 + 1u;
  TF_R(x1,17) TF_R(x1,29) TF_R(x1,16) TF_R(x1,24)
  x0 += ks2; x1 += k0 + 2u;
  TF_R(x1,13) TF_R(x1,15) TF_R(x1,26) TF_R(x1,6)
  x0 += k0; x1 += k1 + 3u;
  TF_R(x1,17) TF_R(x1,29) TF_R(x1,16) TF_R(x1,24)
  x0 += k1; x1 += ks2 + 4u;
  TF_R(x1,13) TF_R(x1,15) TF_R(x1,26) TF_R(x1,6)
  x0 += ks2; x1 += k0 + 5u;
#undef TF_R
  o0 = x0; o1 = x1;
}

__global__ void k_idx(int* __restrict__ idx, unsigned k2a, unsigned k2b,
                      int n, int mask) {
  int j = blockIdx.x * 256 + threadIdx.x;
  if (j >= n) return;
  unsigned o0, o1;
  tf2x32(k2a, k2b, 0u, (unsigned)j, o0, o1);
  idx[j] = (int)((o0 ^ o1) & (unsigned)mask);
}

// positional-encoding table, fp64 math (matches numpy float64 promotion path)
__global__ void k_pe(float* __restrict__ pe) {
  int t = blockIdx.x * 256 + threadIdx.x;   // over 4096*512
  int l = t >> 9, d = t & 511;
  double div = exp((double)(d & ~1) * (-9.210340371976184 / 512.0));
  double ang = (double)l * div;
  pe[t] = (float)((d & 1) ? cos(ang) : sin(ang));
}

// h = x @ emb_w^T + emb_b + pe   (K=64, 16 rows per block)
__global__ __launch_bounds__(256) void k_embed(const float* __restrict__ x,
    const float* __restrict__ W, const float* __restrict__ eb,
    const float* __restrict__ pe, float* __restrict__ out) {
  __shared__ __align__(16) float xs[16][64];
  int r0 = blockIdx.x * 16;
  int t = threadIdx.x;
  ((float4*)&xs[0][0])[t] = ((const float4*)(x + (size_t)r0 * 64))[t];
  __syncthreads();
  int d0 = t, d1 = t + 256;
  float acc0[16], acc1[16];
#pragma unroll
  for (int r = 0; r < 16; r++) { acc0[r] = 0.f; acc1[r] = 0.f; }
  for (int k = 0; k < 64; k++) {
    float w0 = W[d0 * 64 + k], w1 = W[d1 * 64 + k];
#pragma unroll
    for (int r = 0; r < 16; r++) {
      float xv = xs[r][k];
      acc0[r] = fmaf(xv, w0, acc0[r]);
      acc1[r] = fmaf(xv, w1, acc1[r]);
    }
  }
  float eb0 = eb[d0], eb1 = eb[d1];
#pragma unroll
  for (int r = 0; r < 16; r++) {
    int row = r0 + r;
    int l = row & 4095;
    out[(size_t)row * 512 + d0] = acc0[r] + eb0 + pe[(size_t)l * 512 + d0];
    out[(size_t)row * 512 + d1] = acc1[r] + eb1 + pe[(size_t)l * 512 + d1];
  }
}

// per-(b,h,d) mean over L (fp64)
__global__ __launch_bounds__(256) void k_colmean(const float* __restrict__ X,
    float* __restrict__ meanq, int L) {
  int bh = blockIdx.x, b = bh >> 3, h = bh & 7;
  int w = threadIdx.x >> 6, d = threadIdx.x & 63;
  const float* base = X + (size_t)b * L * 512 + h * 64 + d;
  double s = 0.0;
  for (int l = w; l < L; l += 4) s += (double)base[(size_t)l * 512];
  __shared__ double red[4][64];
  red[w][d] = s;
  __syncthreads();
  if (w == 0)
    meanq[bh * 64 + d] = (float)((red[0][d] + red[1][d] + red[2][d] + red[3][d]) / (double)L);
}

// M[b,h,l] = max_s dot(q_l, q_idx[l,s]) - sum_s(...)/L  (fp64, lane = sample)
__global__ __launch_bounds__(256) void k_M(const float* __restrict__ X,
    const int* __restrict__ idx, float* __restrict__ Mout, int L, int u) {
  int w = threadIdx.x >> 6, lane = threadIdx.x & 63;
  int gl = blockIdx.x * 4 + w;
  int l = gl % L, bh = gl / L, b = bh >> 3, h = bh & 7;
  const float* Xbh = X + (size_t)b * L * 512 + h * 64;
  __shared__ float qs[4][64];
  qs[w][lane] = Xbh[(size_t)l * 512 + lane];
  __syncthreads();
  bool act = lane < u;
  double dot = 0.0;
  if (act) {
    int kidx = idx[l * u + lane];
    const float4* kp = (const float4*)(Xbh + (size_t)kidx * 512);
#pragma unroll
    for (int dq = 0; dq < 16; dq++) {
      float4 kv = kp[dq];
      dot += (double)qs[w][dq * 4 + 0] * (double)kv.x;
      dot += (double)qs[w][dq * 4 + 1] * (double)kv.y;
      dot += (double)qs[w][dq * 4 + 2] * (double)kv.z;
      dot += (double)qs[w][dq * 4 + 3] * (double)kv.w;
    }
  }
  double mv = act ? dot : -1e300;
  double sv = act ? dot : 0.0;
  for (int off = 32; off; off >>= 1) {
    mv = fmax(mv, __shfl_xor(mv, off));
    sv += __shfl_xor(sv, off);
  }
  if (lane == 0) Mout[(size_t)bh * L + l] = (float)(mv - sv / (double)L);
}

// iterative top-u argmax per (b,h); tie -> smaller index (matches lax.top_k)
__global__ __launch_bounds__(256) void k_topk(const float* __restrict__ M,
    int* __restrict__ top, int L, int u) {
  __shared__ float mv[4096];
  __shared__ float rv[256];
  __shared__ int ri[256];
  int bh = blockIdx.x, t = threadIdx.x;
  const float* Mr = M + (size_t)bh * L;
  for (int k = t; k < L; k += 256) mv[k] = Mr[k];
  __syncthreads();
  for (int it = 0; it < u; it++) {
    float bv = -1e30f; int bi = 0x7fffffff;
    for (int k = t; k < L; k += 256) {
      float v = mv[k];
      if (v > bv) { bv = v; bi = k; }
    }
    rv[t] = bv; ri[t] = bi;
    __syncthreads();
    for (int off = 128; off; off >>= 1) {
      if (t < off) {
        float v2 = rv[t + off]; int i2 = ri[t + off];
        if (v2 > rv[t] || (v2 == rv[t] && i2 < ri[t])) { rv[t] = v2; ri[t] = i2; }
      }
      __syncthreads();
    }
    if (t == 0) { top[bh * u + it] = ri[0]; mv[ri[0]] = -1e30f; }
    __syncthreads();
  }
}

// ATT <- broadcast mean
__global__ void k_fill(float* __restrict__ A, const float* __restrict__ meanq, int L) {
  size_t t = (size_t)blockIdx.x * 256 + threadIdx.x;
  size_t e = t * 4;
  int dm = (int)(e & 511);
  int b = (int)((e >> 9) / (size_t)L);
  *(float4*)(A + e) = *(const float4*)(meanq + b * 512 + dm);
}

// S[bh,ur,k] = scale * dot(q_red[ur], q_k) for 64-k tile per block
__global__ __launch_bounds__(256) void k_scores(const float* __restrict__ X,
    const int* __restrict__ top, float* __restrict__ S, int L, int u) {
  __shared__ __align__(16) float ktT[64][68];
  __shared__ __align__(16) float qred[48][64];
  int bh = blockIdx.y, b = bh >> 3, h = bh & 7;
  int k0 = blockIdx.x * 64;
  int t = threadIdx.x;
  const float* Xbh = X + (size_t)b * L * 512 + h * 64;
#pragma unroll
  for (int it = 0; it < 4; it++) {
    int lin = t + it * 256;                // (kk, fi) over 64x16
    int kk = lin >> 4, fi = lin & 15;
    float4 v = *(const float4*)(Xbh + (size_t)(k0 + kk) * 512 + fi * 4);
    ktT[fi * 4 + 0][kk] = v.x; ktT[fi * 4 + 1][kk] = v.y;
    ktT[fi * 4 + 2][kk] = v.z; ktT[fi * 4 + 3][kk] = v.w;
  }
#pragma unroll
  for (int it = 0; it < 3; it++) {
    int lin = t + it * 256;                // (ur, fi) over 48x16
    int ur = lin >> 4, fi = lin & 15;
    if (ur < u) {
      int row = top[bh * u + ur];
      *(float4*)(&qred[ur][fi * 4]) = *(const float4*)(Xbh + (size_t)row * 512 + fi * 4);
    } else if (ur < 48) {
      *(float4*)(&qred[ur][fi * 4]) = make_float4(0.f, 0.f, 0.f, 0.f);
    }
  }
  __syncthreads();
  int xq = t & 15, y = t >> 4;
  float acc[3][4];
#pragma unroll
  for (int j = 0; j < 3; j++)
#pragma unroll
    for (int e = 0; e < 4; e++) acc[j][e] = 0.f;
  for (int d = 0; d < 64; d++) {
    float4 kv = *(const float4*)(&ktT[d][xq * 4]);
#pragma unroll
    for (int j = 0; j < 3; j++) {
      float qv = qred[y * 3 + j][d];
      acc[j][0] = fmaf(qv, kv.x, acc[j][0]);
      acc[j][1] = fmaf(qv, kv.y, acc[j][1]);
      acc[j][2] = fmaf(qv, kv.z, acc[j][2]);
      acc[j][3] = fmaf(qv, kv.w, acc[j][3]);
    }
  }
#pragma unroll
  for (int j = 0; j < 3; j++) {
    int ur = y * 3 + j;
    if (ur < u) {
      float4 o = make_float4(acc[j][0] * 0.125f, acc[j][1] * 0.125f,
                             acc[j][2] * 0.125f, acc[j][3] * 0.125f);
      *(float4*)(S + ((size_t)(bh * u + ur)) * L + k0 + xq * 4) = o;
    }
  }
}

// softmax over k + ctx_top row, written straight into ATT at top position.
__global__ __launch_bounds__(256) void k_ctx(const float* __restrict__ X,
    const float* __restrict__ S, const int* __restrict__ top,
    float* __restrict__ A, int L, int u) {
  int ur = blockIdx.x, bh = blockIdx.y, b = bh >> 3, h = bh & 7;
  const float* Srow = S + ((size_t)(bh * u + ur)) * L;
  int t = threadIdx.x;
  __shared__ float wtab[4096];
  __shared__ float rm[256];
  __shared__ double rs[256];
  __shared__ double red[4][64];
  float m = -1e30f;
  for (int k = t; k < L; k += 256) m = fmaxf(m, Srow[k]);
  rm[t] = m; __syncthreads();
  for (int off = 128; off; off >>= 1) {
    if (t < off) rm[t] = fmaxf(rm[t], rm[t + off]);
    __syncthreads();
  }
  float mx = rm[0];
  double s = 0.0;
  for (int k = t; k < L; k += 256) { float e = expf(Srow[k] - mx); wtab[k] = e; s += (double)e; }
  rs[t] = s; __syncthreads();
  for (int off = 128; off; off >>= 1) {
    if (t < off) rs[t] += rs[t + off];
    __syncthreads();
  }
  double inv = 1.0 / rs[0];
  int w = t >> 6, lane = t & 63;
  const float* Xc = X + (size_t)b * L * 512 + h * 64 + lane;
  double a0 = 0.0, a1 = 0.0, a2 = 0.0, a3 = 0.0;
  double a4 = 0.0, a5 = 0.0, a6 = 0.0, a7 = 0.0;
  for (int j = w; j < L; j += 32) {
    float x0 = Xc[(size_t)j * 512];
    float x1 = Xc[(size_t)(j + 4) * 512];
    float x2 = Xc[(size_t)(j + 8) * 512];
    float x3 = Xc[(size_t)(j + 12) * 512];
    float x4 = Xc[(size_t)(j + 16) * 512];
    float x5 = Xc[(size_t)(j + 20) * 512];
    float x6 = Xc[(size_t)(j + 24) * 512];
    float x7 = Xc[(size_t)(j + 28) * 512];
    float p0 = wtab[j],      p1 = wtab[j + 4],  p2 = wtab[j + 8],  p3 = wtab[j + 12];
    float p4 = wtab[j + 16], p5 = wtab[j + 20], p6 = wtab[j + 24], p7 = wtab[j + 28];
    a0 += (double)p0 * (double)x0; a1 += (double)p1 * (double)x1;
    a2 += (double)p2 * (double)x2; a3 += (double)p3 * (double)x3;
    a4 += (double)p4 * (double)x4; a5 += (double)p5 * (double)x5;
    a6 += (double)p6 * (double)x6; a7 += (double)p7 * (double)x7;
  }
  red[w][lane] = ((a0 + a1) + (a2 + a3)) + ((a4 + a5) + (a6 + a7));
  __syncthreads();
  if (w == 0) {
    double tot = (red[0][lane] + red[1][lane] + red[2][lane] + red[3][lane]) * inv;
    int row = top[bh * u + ur];
    A[((size_t)b * L + row) * 512 + h * 64 + lane] = (float)tot;
  }
}

// X <- LN(X + A) * gs + gb, in place; one wave per 512-wide row
__global__ __launch_bounds__(256) void k_ln1(float* __restrict__ X,
    const float* __restrict__ A, const float* __restrict__ gs,
    const float* __restrict__ gb) {
  int w = threadIdx.x >> 6, lane = threadIdx.x & 63;
  int row = blockIdx.x * 4 + w;
  float* xr = X + (size_t)row * 512;
  const float* ar = A + (size_t)row * 512;
  float v[8]; double s = 0.0, s2 = 0.0;
#pragma unroll
  for (int i = 0; i < 8; i++) {
    float val = xr[lane + i * 64] + ar[lane + i * 64];
    v[i] = val; s += (double)val; s2 += (double)val * (double)val;
  }
  for (int off = 32; off; off >>= 1) { s += __shfl_xor(s, off); s2 += __shfl_xor(s2, off); }
  double mu = s * (1.0 / 512.0);
  double var = s2 * (1.0 / 512.0) - mu * mu;
  float rsd = (float)(1.0 / sqrt(var + 1e-5));
  float muf = (float)mu;
#pragma unroll
  for (int i = 0; i < 8; i++) {
    int d = lane + i * 64;
    xr[d] = (v[i] - muf) * rsd * gs[d] + gb[d];
  }
}

// out <- LN(X + Y2); optional pair-pool (distil); one wave per output row
__global__ __launch_bounds__(256) void k_ln2(const float* __restrict__ X,
    const float* __restrict__ Y2, const float* __restrict__ gs,
    const float* __restrict__ gb, float* __restrict__ out, int pool) {
  int w = threadIdx.x >> 6, lane = threadIdx.x & 63;
  int orow = blockIdx.x * 4 + w;
  float o[8] = {0.f,0.f,0.f,0.f,0.f,0.f,0.f,0.f};
  int reps = pool ? 2 : 1;
  for (int p = 0; p < reps; p++) {
    int row = pool ? (orow * 2 + p) : orow;
    const float* xr = X + (size_t)row * 512;
    const float* yr = Y2 + (size_t)row * 512;
    float v[8]; double s = 0.0, s2 = 0.0;
#pragma unroll
    for (int i = 0; i < 8; i++) {
      float val = xr[lane + i * 64] + yr[lane + i * 64];
      v[i] = val; s += (double)val; s2 += (double)val * (double)val;
    }
    for (int off = 32; off; off >>= 1) { s += __shfl_xor(s, off); s2 += __shfl_xor(s2, off); }
    double mu = s * (1.0 / 512.0);
    double var = s2 * (1.0 / 512.0) - mu * mu;
    float rsd = (float)(1.0 / sqrt(var + 1e-5));
    float muf = (float)mu;
#pragma unroll
    for (int i = 0; i < 8; i++)
      o[i] += (v[i] - muf) * rsd * gs[lane + i * 64] + gb[lane + i * 64];
  }
  float sc = pool ? 0.5f : 1.0f;
#pragma unroll
  for (int i = 0; i < 8; i++)
    out[(size_t)orow * 512 + lane + i * 64] = o[i] * sc;
}

// ---------------- bf16x3 plane machinery ----------------
// fp32 matrix [M][K] row-major -> 3 bf16 planes (hi/mid/lo) in MFMA
// fragment-tile order: plane[tile16_m][kblock32][lane64][8 bf16], where
// lane = ((k>>3)&3)*16 + (m&15), j = k&7.  Tile = 1024 B contiguous, so
// k_gemm6 stages tiles with global_load_lds (wave-uniform base + lane*16)
// and reads fragments with linear conflict-free ds_read_b128.

__device__ inline unsigned bsplit(float x, float y, float& rx, float& ry) {
  union { __hip_bfloat162 h; unsigned u; } c;
  c.h = __float22bfloat162_rn(make_float2(x, y));
  rx = x - __uint_as_float(c.u << 16);
  ry = y - __uint_as_float(c.u & 0xffff0000u);
  return c.u;
}

__device__ inline void split3u(float4 v0, float4 v1,
                               uint4& H, uint4& M, uint4& L) {
  float r[8], r2[8]; float d0, d1;
  H.x = bsplit(v0.x, v0.y, r[0], r[1]);
  H.y = bsplit(v0.z, v0.w, r[2], r[3]);
  H.z = bsplit(v1.x, v1.y, r[4], r[5]);
  H.w = bsplit(v1.z, v1.w, r[6], r[7]);
  M.x = bsplit(r[0], r[1], r2[0], r2[1]);
  M.y = bsplit(r[2], r[3], r2[2], r2[3]);
  M.z = bsplit(r[4], r[5], r2[4], r2[5]);
  M.w = bsplit(r[6], r[7], r2[6], r2[7]);
  L.x = bsplit(r2[0], r2[1], d0, d1);
  L.y = bsplit(r2[2], r2[3], d0, d1);
  L.z = bsplit(r2[4], r2[5], d0, d1);
  L.w = bsplit(r2[6], r2[7], d0, d1);
}

// split fp32 [M][K] -> 3 planes frag-tile order. total8 = M*K/8.
__global__ void k_splitX(const float* __restrict__ X, char* __restrict__ P,
                         int K, int total8) {
  int f = blockIdx.x * 256 + threadIdx.x;
  if (f >= total8) return;
  int k8 = f % (K >> 3), m = f / (K >> 3);
  int k = k8 * 8;
  const float* src = X + (size_t)m * K + k;
  float4 v0 = *(const float4*)(src);
  float4 v1 = *(const float4*)(src + 4);
  uint4 H, Md, L;
  split3u(v0, v1, H, Md, L);
  size_t psz = (size_t)total8 * 16;   // M*K*2 bytes per plane
  size_t off = ((size_t)(m >> 4) * (K >> 5) + (k >> 5)) * 1024
             + (size_t)(((k >> 3) & 3) * 256 + (m & 15) * 16);
  *(uint4*)(P + off) = H;
  *(uint4*)(P + psz + off) = Md;
  *(uint4*)(P + 2 * psz + off) = L;
}

__device__ __forceinline__ void async16(void* lds, const void* g) {
  __builtin_amdgcn_global_load_lds(
      (const __attribute__((address_space(1))) uint*)g,
      (__attribute__((address_space(3))) uint*)lds, 16, 0, 0);
}

// C = A @ B^T + bias, A/B as bf16x3 frag-order planes. 6-term bf16x3
// (hh, hm, mh, mm, hl, lh) -> fp32-faithful (same order as rounds 4/5).
// Block tile: (MT*16) x 128, BK=32. 4 waves as 2x2. m97-style 2-barrier
// K-loop with global_load_lds width-16 staging.
// PLANES_OUT: epilogue writes gelu output as frag-order planes (FFN1->FFN2).
template <int MT, int GELU, int PLANES_OUT>
__global__ __launch_bounds__(256) void k_gemm6(const char* __restrict__ AP,
    const char* __restrict__ BP, const float* __restrict__ bias,
    void* __restrict__ Cout, int N, int K) {
  __shared__ __align__(16) char lds[(MT + 8) * 3 * 1024];
  const int t = threadIdx.x;
  const int w = t >> 6, lane = t & 63;
  const int bx = blockIdx.x, by = blockIdx.y;
  const int quad = lane >> 4, rit = lane & 15;
  const int Mrows = gridDim.y * (MT * 16);
  const size_t psA = (size_t)Mrows * K * 2;
  const size_t psB = (size_t)N * K * 2;
  const int KB = K >> 5;
  char* ldsA = lds;
  char* ldsB = lds + MT * 3 * 1024;
  const int wm = (w >> 1) * (MT / 2), wn = (w & 1) * 4;
  f32x4 acc[MT / 2][4];
#pragma unroll
  for (int i = 0; i < MT / 2; i++)
#pragma unroll
    for (int j = 0; j < 4; j++) acc[i][j] = (f32x4){0.f, 0.f, 0.f, 0.f};
  for (int kt = 0; kt < KB; kt++) {
    // stage A: MT*3 tiles; B: 24 tiles. issue q = w + 4r round-robin.
#pragma unroll
    for (int r = 0; r < (MT * 3) / 4; r++) {
      int q = w + 4 * r;
      int p = q / MT, tt = q % MT;
      async16(ldsA + (p * MT + tt) * 1024,
              AP + p * psA + ((size_t)(by * MT + tt) * KB + kt) * 1024 + lane * 16);
    }
#pragma unroll
    for (int r = 0; r < 6; r++) {
      int q = w + 4 * r;
      int p = q >> 3, tt = q & 7;
      async16(ldsB + (p * 8 + tt) * 1024,
              BP + p * psB + ((size_t)(bx * 8 + tt) * KB + kt) * 1024 + lane * 16);
    }
    __syncthreads();
    short8 af[3][MT / 2];
#pragma unroll
    for (int p = 0; p < 3; p++)
#pragma unroll
      for (int mi = 0; mi < MT / 2; mi++)
        af[p][mi] = *(const short8*)(ldsA + (p * MT + wm + mi) * 1024 + lane * 16);
#pragma unroll
    for (int ni = 0; ni < 4; ni++) {
      const char* bb = ldsB + (wn + ni) * 1024 + lane * 16;
      short8 bh = *(const short8*)(bb);
      short8 bm = *(const short8*)(bb + 8192);
      short8 bl = *(const short8*)(bb + 16384);
#pragma unroll
      for (int mi = 0; mi < MT / 2; mi++) {
        f32x4 c = acc[mi][ni];
        c = __builtin_amdgcn_mfma_f32_16x16x32_bf16(af[0][mi], bh, c, 0, 0, 0);
        c = __builtin_amdgcn_mfma_f32_16x16x32_bf16(af[0][mi], bm, c, 0, 0, 0);
        c = __builtin_amdgcn_mfma_f32_16x16x32_bf16(af[1][mi], bh, c, 0, 0, 0);
        c = __builtin_amdgcn_mfma_f32_16x16x32_bf16(af[1][mi], bm, c, 0, 0, 0);
        c = __builtin_amdgcn_mfma_f32_16x16x32_bf16(af[0][mi], bl, c, 0, 0, 0);
        c = __builtin_amdgcn_mfma_f32_16x16x32_bf16(af[2][mi], bh, c, 0, 0, 0);
        acc[mi][ni] = c;
      }
    }
    __syncthreads();
  }
  const int n0 = bx * 128, m_base = by * (MT * 16);
  if (!PLANES_OUT) {
    float* C = (float*)Cout;
#pragma unroll
    for (int mi = 0; mi < MT / 2; mi++) {
      const int gr0 = m_base + (wm + mi) * 16 + quad * 4;
#pragma unroll
      for (int ni = 0; ni < 4; ni++) {
        const int gc = n0 + (wn + ni) * 16 + rit;
        const float bia = bias[gc];
#pragma unroll
        for (int e = 0; e < 4; e++) {
          float v = acc[mi][ni][e] + bia;
          if (GELU) v = 0.5f * v * (1.0f + erff(v * 0.7071067811865476f));
          C[(size_t)(gr0 + e) * N + gc] = v;
        }
      }
    }
  } else {
    // write gelu output as frag-order planes (M = Mrows, "K" = N)
    char* CP = (char*)Cout;
    const size_t psC = (size_t)Mrows * N * 2;
    float* lf = (float*)lds;   // 128 x 64 fp32 = 32 KB scratch
    for (int h = 0; h < 2; h++) {
      __syncthreads();
      if ((w & 1) == h) {
#pragma unroll
        for (int ni = 0; ni < 4; ni++) {
          const float bia = bias[n0 + h * 64 + ni * 16 + rit];
#pragma unroll
          for (int mi = 0; mi < MT / 2; mi++) {
            const int ml0 = (wm + mi) * 16 + quad * 4;
#pragma unroll
            for (int e = 0; e < 4; e++) {
              float v = acc[mi][ni][e] + bia;
              if (GELU) v = 0.5f * v * (1.0f + erff(v * 0.7071067811865476f));
              lf[(ml0 + e) * 64 + ni * 16 + rit] = v;
            }
          }
        }
      }
      __syncthreads();
#pragma unroll
      for (int it = 0; it < (MT * 16 * 8) / 256; it++) {
        int p = it * 256 + t;
        int ml = p >> 3, n8 = p & 7;
        float4 v0 = *(const float4*)&lf[ml * 64 + n8 * 8];
        float4 v1 = *(const float4*)&lf[ml * 64 + n8 * 8 + 4];
        uint4 H, Md, L;
        split3u(v0, v1, H, Md, L);
        int mg = m_base + ml, kg = n0 + h * 64 + n8 * 8;
        size_t off = ((size_t)(mg >> 4) * (N >> 5) + (kg >> 5)) * 1024
                   + (size_t)(((kg >> 3) & 3) * 256 + (mg & 15) * 16);
        *(uint4*)(CP + off) = H;
        *(uint4*)(CP + psC + off) = Md;
        *(uint4*)(CP + 2 * psC + off) = L;
      }
    }
  }
}

extern "C" void kernel_launch(void* const* d_in, const int* in_sizes, int n_in,
                              void* d_out, int out_size, void* d_ws, size_t ws_size,
                              hipStream_t stream) {
  const float* x     = (const float*)d_in[0];
  const float* emb_w = (const float*)d_in[1];
  const float* emb_b = (const float*)d_in[2];
  const float* ln1_s = (const float*)d_in[3];
  const float* ln1_b = (const float*)d_in[4];
  const float* w1    = (const float*)d_in[5];
  const float* b1    = (const float*)d_in[6];
  const float* w2    = (const float*)d_in[7];
  const float* b2    = (const float*)d_in[8];
  const float* ln2_s = (const float*)d_in[9];
  const float* ln2_b = (const float*)d_in[10];
  const float* out_w = (const float*)d_in[11];
  const float* out_b = (const float*)d_in[12];
  float* outp = (float*)d_out;

  char* ws = (char*)d_ws;
  if (ws_size < (212ULL << 20)) return;
  float* PE    = (float*)(ws);                    // 8 MiB, dead after embed
  char*  W1S   = ws;                              // 6 MiB planes, overlay PE
  float* BUF[3] = { (float*)(ws + (8ULL << 20)),
                    (float*)(ws + (72ULL << 20)),
                    (float*)(ws + (136ULL << 20)) };  // 3 x 64 MiB
  char*  W2S   = ws + (200ULL << 20);             // 6 MiB planes
  float* MB    = (float*)(ws + (206ULL << 20));   // 1 MiB
  int*   IDX   = (int*)  (ws + (207ULL << 20));
  int*   TOP   = (int*)  (ws + (208ULL << 20));
  float* MEANQ = (float*)(ws + (208ULL << 20) + (64 << 10));

  k_pe<<<4096 * 512 / 256, 256, 0, stream>>>(PE);
  k_embed<<<(8 * 4096) / 16, 256, 0, stream>>>(x, emb_w, emb_b, PE, BUF[0]);

  const int Ls[3] = {4096, 2048, 1024};
  const int us[3] = {45, 40, 35};
  int xi = 0, ai = 1, yi = 2;
  for (int layer = 0; layer < 3; layer++) {
    const int L = Ls[layer], u = us[layer];
    float* X = BUF[xi]; float* A = BUF[ai]; float* Y = BUF[yi];

    // per-layer weight planes (PE dead after embed)
    k_splitX<<<(2048 * 512 / 8) / 256, 256, 0, stream>>>(
        w1 + (size_t)layer * 2048 * 512, W1S, 512, 2048 * 512 / 8);
    k_splitX<<<(512 * 2048 / 8) / 256, 256, 0, stream>>>(
        w2 + (size_t)layer * 512 * 2048, W2S, 2048, 512 * 2048 / 8);

    unsigned Ka, Kb, k2a, k2b;
    tf2x32(0u, 42u, 0u, (unsigned)layer, Ka, Kb);
    tf2x32(Ka, Kb, 0u, 1u, k2a, k2b);
    const int n = L * u;
    k_idx<<<(n + 255) / 256, 256, 0, stream>>>(IDX, k2a, k2b, n, L - 1);
    k_colmean<<<64, 256, 0, stream>>>(X, MEANQ, L);
    k_M<<<64 * L / 4, 256, 0, stream>>>(X, IDX, MB, L, u);
    k_topk<<<64, 256, 0, stream>>>(MB, TOP, L, u);
    k_fill<<<8 * L / 2, 256, 0, stream>>>(A, MEANQ, L);
    k_scores<<<dim3(L / 64, 64), 256, 0, stream>>>(X, TOP, Y, L, u);
    k_ctx<<<dim3(u, 64), 256, 0, stream>>>(X, Y, TOP, A, L, u);
    k_ln1<<<8 * L / 4, 256, 0, stream>>>(X, A, ln1_s + layer * 512, ln1_b + layer * 512);

    // FFN in 4096-row chunks: YP planes (48 MiB) at Y, XP (12 MiB) at Y+48MiB
    char* YP = (char*)Y;
    char* XP = (char*)Y + (48ULL << 20);
    const int chunks = (8 * L) / 4096;
    for (int c = 0; c < chunks; c++) {
      const float* Xc = X + (size_t)c * 4096 * 512;
      k_splitX<<<(4096 * 512 / 8) / 256, 256, 0, stream>>>(
          Xc, XP, 512, 4096 * 512 / 8);
      k_gemm6<8, 1, 1><<<dim3(16, 32), 256, 0, stream>>>(
          XP, W1S, b1 + layer * 2048, YP, 2048, 512);
      k_gemm6<4, 0, 0><<<dim3(4, 64), 256, 0, stream>>>(
          YP, W2S, b2 + layer * 512, A + (size_t)c * 4096 * 512, 512, 2048);
    }
    if (layer < 2)
      k_ln2<<<8 * (L / 2) / 4, 256, 0, stream>>>(X, A, ln2_s + layer * 512,
                                                 ln2_b + layer * 512, Y, 1);
    else
      k_ln2<<<8 * L / 4, 256, 0, stream>>>(X, A, ln2_s + layer * 512,
                                           ln2_b + layer * 512, Y, 0);
    int tswap = xi; xi = yi; yi = ai; ai = tswap;  // next X = Y
  }
  // final projection: (8192, 512) @ out_w^T + out_b
  char* XFP = (char*)BUF[ai];                      // 24 MiB planes
  char* WOS = W2S;                                 // 1.5 MiB planes
  k_splitX<<<(512 * 512 / 8) / 256, 256, 0, stream>>>(out_w, WOS, 512, 512 * 512 / 8);
  k_splitX<<<(8192 * 512 / 8) / 256, 256, 0, stream>>>(BUF[xi], XFP, 512, 8192 * 512 / 8);
  k_gemm6<8, 0, 0><<<dim3(4, 64), 256, 0, stream>>>(XFP, WOS, out_b, outp, 512, 512);
}

// Round 7
// 3898.318 us; speedup vs baseline: 2.4342x; 1.1097x over previous
//
#include <hip/hip_runtime.h>
#include <hip/hip_bf16.h>
#include <math.h>

// ---- JAX threefry RNG: partitionable, bits = o0 ^ o1 [VERIFIED round 2] ----

typedef short short8 __attribute__((ext_vector_type(8)));
typedef float f32x4 __attribute__((ext_vector_type(4)));
typedef unsigned int uint;

__host__ __device__ inline void tf2x32(unsigned k0, unsigned k1,
                                       unsigned x0, unsigned x1,
                                       unsigned& o0, unsigned& o1) {
  unsigned ks2 = k0 ^ k1 ^ 0x1BD11BDAu;
#define TF_R(x, r) x0 += x1; x1 = ((x1 << (r)) | (x1 >> (32 - (r)))); x1 ^= x0;
  x0 += k0; x1 += k1;
  TF_R(x1,13) TF_R(x1,15) TF_R(x1,26) TF_R(x1,6)
  x0 += k1; x1 += ks2 + 1u;
  TF_R(x1,17) TF_R(x1,29) TF_R(x1,16) TF_R(x1,24)
  x0 += ks2; x1 += k0 + 2u;
  TF_R(x1,13) TF_R(x1,15) TF_R(x1,26) TF_R(x1,6)
  x0 += k0; x1 += k1 + 3u;
  TF_R(x1,17) TF_R(x1,29) TF_R(x1,16) TF_R(x1,24)
  x0 += k1; x1 += ks2 + 4u;
  TF_R(x1,13) TF_R(x1,15) TF_R(x1,26) TF_R(x1,6)
  x0 += ks2; x1 += k0 + 5u;
#undef TF_R
  o0 = x0; o1 = x1;
}

__global__ void k_idx(int* __restrict__ idx, unsigned k2a, unsigned k2b,
                      int n, int mask) {
  int j = blockIdx.x * 256 + threadIdx.x;
  if (j >= n) return;
  unsigned o0, o1;
  tf2x32(k2a, k2b, 0u, (unsigned)j, o0, o1);
  idx[j] = (int)((o0 ^ o1) & (unsigned)mask);
}

// positional-encoding table, fp64 math (matches numpy float64 promotion path)
__global__ void k_pe(float* __restrict__ pe) {
  int t = blockIdx.x * 256 + threadIdx.x;   // over 4096*512
  int l = t >> 9, d = t & 511;
  double div = exp((double)(d & ~1) * (-9.210340371976184 / 512.0));
  double ang = (double)l * div;
  pe[t] = (float)((d & 1) ? cos(ang) : sin(ang));
}

// h = x @ emb_w^T + emb_b + pe   (K=64, 16 rows per block)
__global__ __launch_bounds__(256) void k_embed(const float* __restrict__ x,
    const float* __restrict__ W, const float* __restrict__ eb,
    const float* __restrict__ pe, float* __restrict__ out) {
  __shared__ __align__(16) float xs[16][64];
  int r0 = blockIdx.x * 16;
  int t = threadIdx.x;
  ((float4*)&xs[0][0])[t] = ((const float4*)(x + (size_t)r0 * 64))[t];
  __syncthreads();
  int d0 = t, d1 = t + 256;
  float acc0[16], acc1[16];
#pragma unroll
  for (int r = 0; r < 16; r++) { acc0[r] = 0.f; acc1[r] = 0.f; }
  for (int k = 0; k < 64; k++) {
    float w0 = W[d0 * 64 + k], w1 = W[d1 * 64 + k];
#pragma unroll
    for (int r = 0; r < 16; r++) {
      float xv = xs[r][k];
      acc0[r] = fmaf(xv, w0, acc0[r]);
      acc1[r] = fmaf(xv, w1, acc1[r]);
    }
  }
  float eb0 = eb[d0], eb1 = eb[d1];
#pragma unroll
  for (int r = 0; r < 16; r++) {
    int row = r0 + r;
    int l = row & 4095;
    out[(size_t)row * 512 + d0] = acc0[r] + eb0 + pe[(size_t)l * 512 + d0];
    out[(size_t)row * 512 + d1] = acc1[r] + eb1 + pe[(size_t)l * 512 + d1];
  }
}

// per-(b,h,d) mean over L (fp64)
__global__ __launch_bounds__(256) void k_colmean(const float* __restrict__ X,
    float* __restrict__ meanq, int L) {
  int bh = blockIdx.x, b = bh >> 3, h = bh & 7;
  int w = threadIdx.x >> 6, d = threadIdx.x & 63;
  const float* base = X + (size_t)b * L * 512 + h * 64 + d;
  double s = 0.0;
  for (int l = w; l < L; l += 4) s += (double)base[(size_t)l * 512];
  __shared__ double red[4][64];
  red[w][d] = s;
  __syncthreads();
  if (w == 0)
    meanq[bh * 64 + d] = (float)((red[0][d] + red[1][d] + red[2][d] + red[3][d]) / (double)L);
}

// M[b,h,l] = max_s dot(q_l,k_s) - sum_s(...)/L  (fp64).
// Round-7 layout: lane=(s16,j) so 4 consecutive lanes read 4 consecutive
// float4s of the SAME gathered row -> each gather instr touches 16 packed
// lines (was 45 sparse lines); all 12 gathers issued up-front for ILP.
__global__ __launch_bounds__(256) void k_M(const float* __restrict__ X,
    const int* __restrict__ idx, float* __restrict__ Mout, int L, int u) {
  int w = threadIdx.x >> 6, lane = threadIdx.x & 63;
  int gl = blockIdx.x * 4 + w;
  int l = gl % L, bh = gl / L, b = bh >> 3, h = bh & 7;
  const float* Xbh = X + (size_t)b * L * 512 + h * 64;
  __shared__ float qs[4][64];
  qs[w][lane] = Xbh[(size_t)l * 512 + lane];
  __syncthreads();
  const int s16 = lane >> 2, j = lane & 3;
  float4 qv[4];
#pragma unroll
  for (int c = 0; c < 4; c++) qv[c] = *(const float4*)&qs[w][c * 16 + j * 4];
  const int base = l * u;
  int kx[3];
#pragma unroll
  for (int g = 0; g < 3; g++) {
    int s = g * 16 + s16;
    kx[g] = (s < u) ? idx[base + s] : 0;
  }
  float4 kv[3][4];
#pragma unroll
  for (int g = 0; g < 3; g++) {
    const float* row = Xbh + (size_t)kx[g] * 512 + j * 4;
#pragma unroll
    for (int c = 0; c < 4; c++) kv[g][c] = *(const float4*)(row + c * 16);
  }
  double mv = -1e300, sv = 0.0;
#pragma unroll
  for (int g = 0; g < 3; g++) {
    double acc = 0.0;
#pragma unroll
    for (int c = 0; c < 4; c++) {
      acc += (double)qv[c].x * (double)kv[g][c].x;
      acc += (double)qv[c].y * (double)kv[g][c].y;
      acc += (double)qv[c].z * (double)kv[g][c].z;
      acc += (double)qv[c].w * (double)kv[g][c].w;
    }
    acc += __shfl_xor(acc, 1);
    acc += __shfl_xor(acc, 2);      // all 4 j-lanes now hold dot_s
    if (g * 16 + s16 < u) { mv = fmax(mv, acc); sv += acc; }
  }
  // reduce across the 16 sample-slots (j-quads are identical -> stride-4 only)
  for (int off = 4; off < 64; off <<= 1) {
    mv = fmax(mv, __shfl_xor(mv, off));
    sv += __shfl_xor(sv, off);
  }
  if (lane == 0) Mout[(size_t)bh * L + l] = (float)(mv - sv / (double)L);
}

// iterative top-u argmax per (b,h); tie -> smaller index (matches lax.top_k)
__global__ __launch_bounds__(256) void k_topk(const float* __restrict__ M,
    int* __restrict__ top, int L, int u) {
  __shared__ float mv[4096];
  __shared__ float rv[256];
  __shared__ int ri[256];
  int bh = blockIdx.x, t = threadIdx.x;
  const float* Mr = M + (size_t)bh * L;
  for (int k = t; k < L; k += 256) mv[k] = Mr[k];
  __syncthreads();
  for (int it = 0; it < u; it++) {
    float bv = -1e30f; int bi = 0x7fffffff;
    for (int k = t; k < L; k += 256) {
      float v = mv[k];
      if (v > bv) { bv = v; bi = k; }
    }
    rv[t] = bv; ri[t] = bi;
    __syncthreads();
    for (int off = 128; off; off >>= 1) {
      if (t < off) {
        float v2 = rv[t + off]; int i2 = ri[t + off];
        if (v2 > rv[t] || (v2 == rv[t] && i2 < ri[t])) { rv[t] = v2; ri[t] = i2; }
      }
      __syncthreads();
    }
    if (t == 0) { top[bh * u + it] = ri[0]; mv[ri[0]] = -1e30f; }
    __syncthreads();
  }
}

// ATT <- broadcast mean
__global__ void k_fill(float* __restrict__ A, const float* __restrict__ meanq, int L) {
  size_t t = (size_t)blockIdx.x * 256 + threadIdx.x;
  size_t e = t * 4;
  int dm = (int)(e & 511);
  int b = (int)((e >> 9) / (size_t)L);
  *(float4*)(A + e) = *(const float4*)(meanq + b * 512 + dm);
}

// S[bh,ur,k] = scale * dot(q_red[ur], q_k) for 64-k tile per block
__global__ __launch_bounds__(256) void k_scores(const float* __restrict__ X,
    const int* __restrict__ top, float* __restrict__ S, int L, int u) {
  __shared__ __align__(16) float ktT[64][68];
  __shared__ __align__(16) float qred[48][64];
  int bh = blockIdx.y, b = bh >> 3, h = bh & 7;
  int k0 = blockIdx.x * 64;
  int t = threadIdx.x;
  const float* Xbh = X + (size_t)b * L * 512 + h * 64;
#pragma unroll
  for (int it = 0; it < 4; it++) {
    int lin = t + it * 256;                // (kk, fi) over 64x16
    int kk = lin >> 4, fi = lin & 15;
    float4 v = *(const float4*)(Xbh + (size_t)(k0 + kk) * 512 + fi * 4);
    ktT[fi * 4 + 0][kk] = v.x; ktT[fi * 4 + 1][kk] = v.y;
    ktT[fi * 4 + 2][kk] = v.z; ktT[fi * 4 + 3][kk] = v.w;
  }
#pragma unroll
  for (int it = 0; it < 3; it++) {
    int lin = t + it * 256;                // (ur, fi) over 48x16
    int ur = lin >> 4, fi = lin & 15;
    if (ur < u) {
      int row = top[bh * u + ur];
      *(float4*)(&qred[ur][fi * 4]) = *(const float4*)(Xbh + (size_t)row * 512 + fi * 4);
    } else if (ur < 48) {
      *(float4*)(&qred[ur][fi * 4]) = make_float4(0.f, 0.f, 0.f, 0.f);
    }
  }
  __syncthreads();
  int xq = t & 15, y = t >> 4;
  float acc[3][4];
#pragma unroll
  for (int j = 0; j < 3; j++)
#pragma unroll
    for (int e = 0; e < 4; e++) acc[j][e] = 0.f;
  for (int d = 0; d < 64; d++) {
    float4 kv = *(const float4*)(&ktT[d][xq * 4]);
#pragma unroll
    for (int j = 0; j < 3; j++) {
      float qv = qred[y * 3 + j][d];
      acc[j][0] = fmaf(qv, kv.x, acc[j][0]);
      acc[j][1] = fmaf(qv, kv.y, acc[j][1]);
      acc[j][2] = fmaf(qv, kv.z, acc[j][2]);
      acc[j][3] = fmaf(qv, kv.w, acc[j][3]);
    }
  }
#pragma unroll
  for (int j = 0; j < 3; j++) {
    int ur = y * 3 + j;
    if (ur < u) {
      float4 o = make_float4(acc[j][0] * 0.125f, acc[j][1] * 0.125f,
                             acc[j][2] * 0.125f, acc[j][3] * 0.125f);
      *(float4*)(S + ((size_t)(bh * u + ur)) * L + k0 + xq * 4) = o;
    }
  }
}

// softmax over k + ctx_top row, written straight into ATT at top position.
__global__ __launch_bounds__(256) void k_ctx(const float* __restrict__ X,
    const float* __restrict__ S, const int* __restrict__ top,
    float* __restrict__ A, int L, int u) {
  int ur = blockIdx.x, bh = blockIdx.y, b = bh >> 3, h = bh & 7;
  const float* Srow = S + ((size_t)(bh * u + ur)) * L;
  int t = threadIdx.x;
  __shared__ float wtab[4096];
  __shared__ float rm[256];
  __shared__ double rs[256];
  __shared__ double red[4][64];
  float m = -1e30f;
  for (int k = t; k < L; k += 256) m = fmaxf(m, Srow[k]);
  rm[t] = m; __syncthreads();
  for (int off = 128; off; off >>= 1) {
    if (t < off) rm[t] = fmaxf(rm[t], rm[t + off]);
    __syncthreads();
  }
  float mx = rm[0];
  double s = 0.0;
  for (int k = t; k < L; k += 256) { float e = expf(Srow[k] - mx); wtab[k] = e; s += (double)e; }
  rs[t] = s; __syncthreads();
  for (int off = 128; off; off >>= 1) {
    if (t < off) rs[t] += rs[t + off];
    __syncthreads();
  }
  double inv = 1.0 / rs[0];
  int w = t >> 6, lane = t & 63;
  const float* Xc = X + (size_t)b * L * 512 + h * 64 + lane;
  double a0 = 0.0, a1 = 0.0, a2 = 0.0, a3 = 0.0;
  double a4 = 0.0, a5 = 0.0, a6 = 0.0, a7 = 0.0;
  for (int j = w; j < L; j += 32) {
    float x0 = Xc[(size_t)j * 512];
    float x1 = Xc[(size_t)(j + 4) * 512];
    float x2 = Xc[(size_t)(j + 8) * 512];
    float x3 = Xc[(size_t)(j + 12) * 512];
    float x4 = Xc[(size_t)(j + 16) * 512];
    float x5 = Xc[(size_t)(j + 20) * 512];
    float x6 = Xc[(size_t)(j + 24) * 512];
    float x7 = Xc[(size_t)(j + 28) * 512];
    float p0 = wtab[j],      p1 = wtab[j + 4],  p2 = wtab[j + 8],  p3 = wtab[j + 12];
    float p4 = wtab[j + 16], p5 = wtab[j + 20], p6 = wtab[j + 24], p7 = wtab[j + 28];
    a0 += (double)p0 * (double)x0; a1 += (double)p1 * (double)x1;
    a2 += (double)p2 * (double)x2; a3 += (double)p3 * (double)x3;
    a4 += (double)p4 * (double)x4; a5 += (double)p5 * (double)x5;
    a6 += (double)p6 * (double)x6; a7 += (double)p7 * (double)x7;
  }
  red[w][lane] = ((a0 + a1) + (a2 + a3)) + ((a4 + a5) + (a6 + a7));
  __syncthreads();
  if (w == 0) {
    double tot = (red[0][lane] + red[1][lane] + red[2][lane] + red[3][lane]) * inv;
    int row = top[bh * u + ur];
    A[((size_t)b * L + row) * 512 + h * 64 + lane] = (float)tot;
  }
}

// X <- LN(X + A) * gs + gb, in place; one wave per 512-wide row
__global__ __launch_bounds__(256) void k_ln1(float* __restrict__ X,
    const float* __restrict__ A, const float* __restrict__ gs,
    const float* __restrict__ gb) {
  int w = threadIdx.x >> 6, lane = threadIdx.x & 63;
  int row = blockIdx.x * 4 + w;
  float* xr = X + (size_t)row * 512;
  const float* ar = A + (size_t)row * 512;
  float v[8]; double s = 0.0, s2 = 0.0;
#pragma unroll
  for (int i = 0; i < 8; i++) {
    float val = xr[lane + i * 64] + ar[lane + i * 64];
    v[i] = val; s += (double)val; s2 += (double)val * (double)val;
  }
  for (int off = 32; off; off >>= 1) { s += __shfl_xor(s, off); s2 += __shfl_xor(s2, off); }
  double mu = s * (1.0 / 512.0);
  double var = s2 * (1.0 / 512.0) - mu * mu;
  float rsd = (float)(1.0 / sqrt(var + 1e-5));
  float muf = (float)mu;
#pragma unroll
  for (int i = 0; i < 8; i++) {
    int d = lane + i * 64;
    xr[d] = (v[i] - muf) * rsd * gs[d] + gb[d];
  }
}

// out <- LN(X + Y2); optional pair-pool (distil); one wave per output row
__global__ __launch_bounds__(256) void k_ln2(const float* __restrict__ X,
    const float* __restrict__ Y2, const float* __restrict__ gs,
    const float* __restrict__ gb, float* __restrict__ out, int pool) {
  int w = threadIdx.x >> 6, lane = threadIdx.x & 63;
  int orow = blockIdx.x * 4 + w;
  float o[8] = {0.f,0.f,0.f,0.f,0.f,0.f,0.f,0.f};
  int reps = pool ? 2 : 1;
  for (int p = 0; p < reps; p++) {
    int row = pool ? (orow * 2 + p) : orow;
    const float* xr = X + (size_t)row * 512;
    const float* yr = Y2 + (size_t)row * 512;
    float v[8]; double s = 0.0, s2 = 0.0;
#pragma unroll
    for (int i = 0; i < 8; i++) {
      float val = xr[lane + i * 64] + yr[lane + i * 64];
      v[i] = val; s += (double)val; s2 += (double)val * (double)val;
    }
    for (int off = 32; off; off >>= 1) { s += __shfl_xor(s, off); s2 += __shfl_xor(s2, off); }
    double mu = s * (1.0 / 512.0);
    double var = s2 * (1.0 / 512.0) - mu * mu;
    float rsd = (float)(1.0 / sqrt(var + 1e-5));
    float muf = (float)mu;
#pragma unroll
    for (int i = 0; i < 8; i++)
      o[i] += (v[i] - muf) * rsd * gs[lane + i * 64] + gb[lane + i * 64];
  }
  float sc = pool ? 0.5f : 1.0f;
#pragma unroll
  for (int i = 0; i < 8; i++)
    out[(size_t)orow * 512 + lane + i * 64] = o[i] * sc;
}

// ---------------- bf16x3 plane machinery ----------------
// fp32 matrix [M][K] row-major -> 3 bf16 planes (hi/mid/lo) in MFMA
// fragment-tile order: plane[tile16_m][kblock32][lane64][8 bf16], where
// lane = ((k>>3)&3)*16 + (m&15), j = k&7.  Tile = 1024 B contiguous, so
// k_gemm6 stages tiles with global_load_lds (wave-uniform base + lane*16)
// and reads fragments with linear conflict-free ds_read_b128.

__device__ inline unsigned bsplit(float x, float y, float& rx, float& ry) {
  union { __hip_bfloat162 h; unsigned u; } c;
  c.h = __float22bfloat162_rn(make_float2(x, y));
  rx = x - __uint_as_float(c.u << 16);
  ry = y - __uint_as_float(c.u & 0xffff0000u);
  return c.u;
}

__device__ inline void split3u(float4 v0, float4 v1,
                               uint4& H, uint4& M, uint4& L) {
  float r[8], r2[8]; float d0, d1;
  H.x = bsplit(v0.x, v0.y, r[0], r[1]);
  H.y = bsplit(v0.z, v0.w, r[2], r[3]);
  H.z = bsplit(v1.x, v1.y, r[4], r[5]);
  H.w = bsplit(v1.z, v1.w, r[6], r[7]);
  M.x = bsplit(r[0], r[1], r2[0], r2[1]);
  M.y = bsplit(r[2], r[3], r2[2], r2[3]);
  M.z = bsplit(r[4], r[5], r2[4], r2[5]);
  M.w = bsplit(r[6], r[7], r2[6], r2[7]);
  L.x = bsplit(r2[0], r2[1], d0, d1);
  L.y = bsplit(r2[2], r2[3], d0, d1);
  L.z = bsplit(r2[4], r2[5], d0, d1);
  L.w = bsplit(r2[6], r2[7], d0, d1);
}

// split fp32 [M][K] -> 3 planes frag-tile order. total8 = M*K/8.
__global__ void k_splitX(const float* __restrict__ X, char* __restrict__ P,
                         int K, int total8) {
  int f = blockIdx.x * 256 + threadIdx.x;
  if (f >= total8) return;
  int k8 = f % (K >> 3), m = f / (K >> 3);
  int k = k8 * 8;
  const float* src = X + (size_t)m * K + k;
  float4 v0 = *(const float4*)(src);
  float4 v1 = *(const float4*)(src + 4);
  uint4 H, Md, L;
  split3u(v0, v1, H, Md, L);
  size_t psz = (size_t)total8 * 16;   // M*K*2 bytes per plane
  size_t off = ((size_t)(m >> 4) * (K >> 5) + (k >> 5)) * 1024
             + (size_t)(((k >> 3) & 3) * 256 + (m & 15) * 16);
  *(uint4*)(P + off) = H;
  *(uint4*)(P + psz + off) = Md;
  *(uint4*)(P + 2 * psz + off) = L;
}

__device__ __forceinline__ void async16(void* lds, const void* g) {
  __builtin_amdgcn_global_load_lds(
      (const __attribute__((address_space(1))) uint*)g,
      (__attribute__((address_space(3))) uint*)lds, 16, 0, 0);
}

// C = A @ B^T + bias, A/B as bf16x3 frag-order planes. 6-term bf16x3
// (hh, hm, mh, mm, hl, lh) -> fp32-faithful (same order as rounds 4/5).
// Block tile: (MT*16) x 128, BK=32. 4 waves as 2x2. m97-style 2-barrier
// K-loop with global_load_lds width-16 staging.
// PLANES_OUT: epilogue writes gelu output as frag-order planes (FFN1->FFN2).
template <int MT, int GELU, int PLANES_OUT>
__global__ __launch_bounds__(256) void k_gemm6(const char* __restrict__ AP,
    const char* __restrict__ BP, const float* __restrict__ bias,
    void* __restrict__ Cout, int N, int K) {
  __shared__ __align__(16) char lds[(MT + 8) * 3 * 1024];
  const int t = threadIdx.x;
  const int w = t >> 6, lane = t & 63;
  const int bx = blockIdx.x, by = blockIdx.y;
  const int quad = lane >> 4, rit = lane & 15;
  const int Mrows = gridDim.y * (MT * 16);
  const size_t psA = (size_t)Mrows * K * 2;
  const size_t psB = (size_t)N * K * 2;
  const int KB = K >> 5;
  char* ldsA = lds;
  char* ldsB = lds + MT * 3 * 1024;
  const int wm = (w >> 1) * (MT / 2), wn = (w & 1) * 4;
  f32x4 acc[MT / 2][4];
#pragma unroll
  for (int i = 0; i < MT / 2; i++)
#pragma unroll
    for (int j = 0; j < 4; j++) acc[i][j] = (f32x4){0.f, 0.f, 0.f, 0.f};
  for (int kt = 0; kt < KB; kt++) {
    // stage A: MT*3 tiles; B: 24 tiles. issue q = w + 4r round-robin.
#pragma unroll
    for (int r = 0; r < (MT * 3) / 4; r++) {
      int q = w + 4 * r;
      int p = q / MT, tt = q % MT;
      async16(ldsA + (p * MT + tt) * 1024,
              AP + p * psA + ((size_t)(by * MT + tt) * KB + kt) * 1024 + lane * 16);
    }
#pragma unroll
    for (int r = 0; r < 6; r++) {
      int q = w + 4 * r;
      int p = q >> 3, tt = q & 7;
      async16(ldsB + (p * 8 + tt) * 1024,
              BP + p * psB + ((size_t)(bx * 8 + tt) * KB + kt) * 1024 + lane * 16);
    }
    __syncthreads();
    short8 af[3][MT / 2];
#pragma unroll
    for (int p = 0; p < 3; p++)
#pragma unroll
      for (int mi = 0; mi < MT / 2; mi++)
        af[p][mi] = *(const short8*)(ldsA + (p * MT + wm + mi) * 1024 + lane * 16);
#pragma unroll
    for (int ni = 0; ni < 4; ni++) {
      const char* bb = ldsB + (wn + ni) * 1024 + lane * 16;
      short8 bh = *(const short8*)(bb);
      short8 bm = *(const short8*)(bb + 8192);
      short8 bl = *(const short8*)(bb + 16384);
#pragma unroll
      for (int mi = 0; mi < MT / 2; mi++) {
        f32x4 c = acc[mi][ni];
        c = __builtin_amdgcn_mfma_f32_16x16x32_bf16(af[0][mi], bh, c, 0, 0, 0);
        c = __builtin_amdgcn_mfma_f32_16x16x32_bf16(af[0][mi], bm, c, 0, 0, 0);
        c = __builtin_amdgcn_mfma_f32_16x16x32_bf16(af[1][mi], bh, c, 0, 0, 0);
        c = __builtin_amdgcn_mfma_f32_16x16x32_bf16(af[1][mi], bm, c, 0, 0, 0);
        c = __builtin_amdgcn_mfma_f32_16x16x32_bf16(af[0][mi], bl, c, 0, 0, 0);
        c = __builtin_amdgcn_mfma_f32_16x16x32_bf16(af[2][mi], bh, c, 0, 0, 0);
        acc[mi][ni] = c;
      }
    }
    __syncthreads();
  }
  const int n0 = bx * 128, m_base = by * (MT * 16);
  if (!PLANES_OUT) {
    float* C = (float*)Cout;
#pragma unroll
    for (int mi = 0; mi < MT / 2; mi++) {
      const int gr0 = m_base + (wm + mi) * 16 + quad * 4;
#pragma unroll
      for (int ni = 0; ni < 4; ni++) {
        const int gc = n0 + (wn + ni) * 16 + rit;
        const float bia = bias[gc];
#pragma unroll
        for (int e = 0; e < 4; e++) {
          float v = acc[mi][ni][e] + bia;
          if (GELU) v = 0.5f * v * (1.0f + erff(v * 0.7071067811865476f));
          C[(size_t)(gr0 + e) * N + gc] = v;
        }
      }
    }
  } else {
    // write gelu output as frag-order planes (M = Mrows, "K" = N)
    char* CP = (char*)Cout;
    const size_t psC = (size_t)Mrows * N * 2;
    float* lf = (float*)lds;   // 128 x 64 fp32 = 32 KB scratch
    for (int h = 0; h < 2; h++) {
      __syncthreads();
      if ((w & 1) == h) {
#pragma unroll
        for (int ni = 0; ni < 4; ni++) {
          const float bia = bias[n0 + h * 64 + ni * 16 + rit];
#pragma unroll
          for (int mi = 0; mi < MT / 2; mi++) {
            const int ml0 = (wm + mi) * 16 + quad * 4;
#pragma unroll
            for (int e = 0; e < 4; e++) {
              float v = acc[mi][ni][e] + bia;
              if (GELU) v = 0.5f * v * (1.0f + erff(v * 0.7071067811865476f));
              lf[(ml0 + e) * 64 + ni * 16 + rit] = v;
            }
          }
        }
      }
      __syncthreads();
#pragma unroll
      for (int it = 0; it < (MT * 16 * 8) / 256; it++) {
        int p = it * 256 + t;
        int ml = p >> 3, n8 = p & 7;
        float4 v0 = *(const float4*)&lf[ml * 64 + n8 * 8];
        float4 v1 = *(const float4*)&lf[ml * 64 + n8 * 8 + 4];
        uint4 H, Md, L;
        split3u(v0, v1, H, Md, L);
        int mg = m_base + ml, kg = n0 + h * 64 + n8 * 8;
        size_t off = ((size_t)(mg >> 4) * (N >> 5) + (kg >> 5)) * 1024
                   + (size_t)(((kg >> 3) & 3) * 256 + (mg & 15) * 16);
        *(uint4*)(CP + off) = H;
        *(uint4*)(CP + psC + off) = Md;
        *(uint4*)(CP + 2 * psC + off) = L;
      }
    }
  }
}

extern "C" void kernel_launch(void* const* d_in, const int* in_sizes, int n_in,
                              void* d_out, int out_size, void* d_ws, size_t ws_size,
                              hipStream_t stream) {
  const float* x     = (const float*)d_in[0];
  const float* emb_w = (const float*)d_in[1];
  const float* emb_b = (const float*)d_in[2];
  const float* ln1_s = (const float*)d_in[3];
  const float* ln1_b = (const float*)d_in[4];
  const float* w1    = (const float*)d_in[5];
  const float* b1    = (const float*)d_in[6];
  const float* w2    = (const float*)d_in[7];
  const float* b2    = (const float*)d_in[8];
  const float* ln2_s = (const float*)d_in[9];
  const float* ln2_b = (const float*)d_in[10];
  const float* out_w = (const float*)d_in[11];
  const float* out_b = (const float*)d_in[12];
  float* outp = (float*)d_out;

  char* ws = (char*)d_ws;
  if (ws_size < (212ULL << 20)) return;
  float* PE    = (float*)(ws);                    // 8 MiB, dead after embed
  char*  W1S   = ws;                              // 6 MiB planes, overlay PE
  float* BUF[3] = { (float*)(ws + (8ULL << 20)),
                    (float*)(ws + (72ULL << 20)),
                    (float*)(ws + (136ULL << 20)) };  // 3 x 64 MiB
  char*  W2S   = ws + (200ULL << 20);             // 6 MiB planes
  float* MB    = (float*)(ws + (206ULL << 20));   // 1 MiB
  int*   IDX   = (int*)  (ws + (207ULL << 20));
  int*   TOP   = (int*)  (ws + (208ULL << 20));
  float* MEANQ = (float*)(ws + (208ULL << 20) + (64 << 10));

  k_pe<<<4096 * 512 / 256, 256, 0, stream>>>(PE);
  k_embed<<<(8 * 4096) / 16, 256, 0, stream>>>(x, emb_w, emb_b, PE, BUF[0]);

  const int Ls[3] = {4096, 2048, 1024};
  const int us[3] = {45, 40, 35};
  int xi = 0, ai = 1, yi = 2;
  for (int layer = 0; layer < 3; layer++) {
    const int L = Ls[layer], u = us[layer];
    float* X = BUF[xi]; float* A = BUF[ai]; float* Y = BUF[yi];

    // per-layer weight planes (PE dead after embed)
    k_splitX<<<(2048 * 512 / 8) / 256, 256, 0, stream>>>(
        w1 + (size_t)layer * 2048 * 512, W1S, 512, 2048 * 512 / 8);
    k_splitX<<<(512 * 2048 / 8) / 256, 256, 0, stream>>>(
        w2 + (size_t)layer * 512 * 2048, W2S, 2048, 512 * 2048 / 8);

    unsigned Ka, Kb, k2a, k2b;
    tf2x32(0u, 42u, 0u, (unsigned)layer, Ka, Kb);
    tf2x32(Ka, Kb, 0u, 1u, k2a, k2b);
    const int n = L * u;
    k_idx<<<(n + 255) / 256, 256, 0, stream>>>(IDX, k2a, k2b, n, L - 1);
    k_colmean<<<64, 256, 0, stream>>>(X, MEANQ, L);
    k_M<<<64 * L / 4, 256, 0, stream>>>(X, IDX, MB, L, u);
    k_topk<<<64, 256, 0, stream>>>(MB, TOP, L, u);
    k_fill<<<8 * L / 2, 256, 0, stream>>>(A, MEANQ, L);
    k_scores<<<dim3(L / 64, 64), 256, 0, stream>>>(X, TOP, Y, L, u);
    k_ctx<<<dim3(u, 64), 256, 0, stream>>>(X, Y, TOP, A, L, u);
    k_ln1<<<8 * L / 4, 256, 0, stream>>>(X, A, ln1_s + layer * 512, ln1_b + layer * 512);

    // FFN in 4096-row chunks: YP planes (48 MiB) at Y, XP (12 MiB) at Y+48MiB
    char* YP = (char*)Y;
    char* XP = (char*)Y + (48ULL << 20);
    const int chunks = (8 * L) / 4096;
    for (int c = 0; c < chunks; c++) {
      const float* Xc = X + (size_t)c * 4096 * 512;
      k_splitX<<<(4096 * 512 / 8) / 256, 256, 0, stream>>>(
          Xc, XP, 512, 4096 * 512 / 8);
      k_gemm6<8, 1, 1><<<dim3(16, 32), 256, 0, stream>>>(
          XP, W1S, b1 + layer * 2048, YP, 2048, 512);
      k_gemm6<4, 0, 0><<<dim3(4, 64), 256, 0, stream>>>(
          YP, W2S, b2 + layer * 512, A + (size_t)c * 4096 * 512, 512, 2048);
    }
    if (layer < 2)
      k_ln2<<<8 * (L / 2) / 4, 256, 0, stream>>>(X, A, ln2_s + layer * 512,
                                                 ln2_b + layer * 512, Y, 1);
    else
      k_ln2<<<8 * L / 4, 256, 0, stream>>>(X, A, ln2_s + layer * 512,
                                           ln2_b + layer * 512, Y, 0);
    int tswap = xi; xi = yi; yi = ai; ai = tswap;  // next X = Y
  }
  // final projection: (8192, 512) @ out_w^T + out_b
  char* XFP = (char*)BUF[ai];                      // 24 MiB planes
  char* WOS = W2S;                                 // 1.5 MiB planes
  k_splitX<<<(512 * 512 / 8) / 256, 256, 0, stream>>>(out_w, WOS, 512, 512 * 512 / 8);
  k_splitX<<<(8192 * 512 / 8) / 256, 256, 0, stream>>>(BUF[xi], XFP, 512, 8192 * 512 / 8);
  k_gemm6<8, 0, 0><<<dim3(4, 64), 256, 0, stream>>>(XFP, WOS, out_b, outp, 512, 512);
}

// Round 8
// 3503.399 us; speedup vs baseline: 2.7086x; 1.1127x over previous
//
#include <hip/hip_runtime.h>
#include <hip/hip_bf16.h>
#include <math.h>

// ---- JAX threefry RNG: partitionable, bits = o0 ^ o1 [VERIFIED round 2] ----

typedef short short8 __attribute__((ext_vector_type(8)));
typedef float f32x4 __attribute__((ext_vector_type(4)));
typedef unsigned int uint;

__host__ __device__ inline void tf2x32(unsigned k0, unsigned k1,
                                       unsigned x0, unsigned x1,
                                       unsigned& o0, unsigned& o1) {
  unsigned ks2 = k0 ^ k1 ^ 0x1BD11BDAu;
#define TF_R(x, r) x0 += x1; x1 = ((x1 << (r)) | (x1 >> (32 - (r)))); x1 ^= x0;
  x0 += k0; x1 += k1;
  TF_R(x1,13) TF_R(x1,15) TF_R(x1,26) TF_R(x1,6)
  x0 += k1; x1 += ks2 + 1u;
  TF_R(x1,17) TF_R(x1,29) TF_R(x1,16) TF_R(x1,24)
  x0 += ks2; x1 += k0 + 2u;
  TF_R(x1,13) TF_R(x1,15) TF_R(x1,26) TF_R(x1,6)
  x0 += k0; x1 += k1 + 3u;
  TF_R(x1,17) TF_R(x1,29) TF_R(x1,16) TF_R(x1,24)
  x0 += k1; x1 += ks2 + 4u;
  TF_R(x1,13) TF_R(x1,15) TF_R(x1,26) TF_R(x1,6)
  x0 += ks2; x1 += k0 + 5u;
#undef TF_R
  o0 = x0; o1 = x1;
}

__global__ void k_idx(int* __restrict__ idx, unsigned k2a, unsigned k2b,
                      int n, int mask) {
  int j = blockIdx.x * 256 + threadIdx.x;
  if (j >= n) return;
  unsigned o0, o1;
  tf2x32(k2a, k2b, 0u, (unsigned)j, o0, o1);
  idx[j] = (int)((o0 ^ o1) & (unsigned)mask);
}

// positional-encoding table, fp64 math (matches numpy float64 promotion path)
__global__ void k_pe(float* __restrict__ pe) {
  int t = blockIdx.x * 256 + threadIdx.x;   // over 4096*512
  int l = t >> 9, d = t & 511;
  double div = exp((double)(d & ~1) * (-9.210340371976184 / 512.0));
  double ang = (double)l * div;
  pe[t] = (float)((d & 1) ? cos(ang) : sin(ang));
}

// h = x @ emb_w^T + emb_b + pe   (K=64, 16 rows per block)
__global__ __launch_bounds__(256) void k_embed(const float* __restrict__ x,
    const float* __restrict__ W, const float* __restrict__ eb,
    const float* __restrict__ pe, float* __restrict__ out) {
  __shared__ __align__(16) float xs[16][64];
  int r0 = blockIdx.x * 16;
  int t = threadIdx.x;
  ((float4*)&xs[0][0])[t] = ((const float4*)(x + (size_t)r0 * 64))[t];
  __syncthreads();
  int d0 = t, d1 = t + 256;
  float acc0[16], acc1[16];
#pragma unroll
  for (int r = 0; r < 16; r++) { acc0[r] = 0.f; acc1[r] = 0.f; }
  for (int k = 0; k < 64; k++) {
    float w0 = W[d0 * 64 + k], w1 = W[d1 * 64 + k];
#pragma unroll
    for (int r = 0; r < 16; r++) {
      float xv = xs[r][k];
      acc0[r] = fmaf(xv, w0, acc0[r]);
      acc1[r] = fmaf(xv, w1, acc1[r]);
    }
  }
  float eb0 = eb[d0], eb1 = eb[d1];
#pragma unroll
  for (int r = 0; r < 16; r++) {
    int row = r0 + r;
    int l = row & 4095;
    out[(size_t)row * 512 + d0] = acc0[r] + eb0 + pe[(size_t)l * 512 + d0];
    out[(size_t)row * 512 + d1] = acc1[r] + eb1 + pe[(size_t)l * 512 + d1];
  }
}

// column-mean phase 1: per-(seg,bh) fp64 partial sums (grid saturates CUs)
__global__ __launch_bounds__(256) void k_colmean1(const float* __restrict__ X,
    double* __restrict__ part, int L, int S) {
  int seg = blockIdx.x, bh = blockIdx.y, b = bh >> 3, h = bh & 7;
  int w = threadIdx.x >> 6, d = threadIdx.x & 63;
  int rows = L / S, r0 = seg * rows;
  const float* base = X + (size_t)b * L * 512 + h * 64 + d;
  double s = 0.0;
  for (int l = r0 + w; l < r0 + rows; l += 4) s += (double)base[(size_t)l * 512];
  __shared__ double red[4][64];
  red[w][d] = s;
  __syncthreads();
  if (w == 0)
    part[((size_t)bh * S + seg) * 64 + d] =
        red[0][d] + red[1][d] + red[2][d] + red[3][d];
}

// column-mean phase 2: reduce S segments, divide by L
__global__ void k_colmean2(const double* __restrict__ part,
    float* __restrict__ meanq, int L, int S) {
  int bh = blockIdx.x, d = threadIdx.x;
  const double* p = part + (size_t)bh * S * 64 + d;
  double s = 0.0;
  for (int seg = 0; seg < S; seg++) s += p[seg * 64];
  meanq[bh * 64 + d] = (float)(s / (double)L);
}

// M[b,h,l] = max_s dot(q_l,k_s) - sum_s(...)/L  (fp64).
// lane=(s16,j): 4 consecutive lanes read 4 consecutive float4s of the SAME
// gathered row -> packed lines; all 12 gathers issued up-front for ILP.
__global__ __launch_bounds__(256) void k_M(const float* __restrict__ X,
    const int* __restrict__ idx, float* __restrict__ Mout, int L, int u) {
  int w = threadIdx.x >> 6, lane = threadIdx.x & 63;
  int gl = blockIdx.x * 4 + w;
  int l = gl % L, bh = gl / L, b = bh >> 3, h = bh & 7;
  const float* Xbh = X + (size_t)b * L * 512 + h * 64;
  __shared__ float qs[4][64];
  qs[w][lane] = Xbh[(size_t)l * 512 + lane];
  __syncthreads();
  const int s16 = lane >> 2, j = lane & 3;
  float4 qv[4];
#pragma unroll
  for (int c = 0; c < 4; c++) qv[c] = *(const float4*)&qs[w][c * 16 + j * 4];
  const int base = l * u;
  int kx[3];
#pragma unroll
  for (int g = 0; g < 3; g++) {
    int s = g * 16 + s16;
    kx[g] = (s < u) ? idx[base + s] : 0;
  }
  float4 kv[3][4];
#pragma unroll
  for (int g = 0; g < 3; g++) {
    const float* row = Xbh + (size_t)kx[g] * 512 + j * 4;
#pragma unroll
    for (int c = 0; c < 4; c++) kv[g][c] = *(const float4*)(row + c * 16);
  }
  double mv = -1e300, sv = 0.0;
#pragma unroll
  for (int g = 0; g < 3; g++) {
    double acc = 0.0;
#pragma unroll
    for (int c = 0; c < 4; c++) {
      acc += (double)qv[c].x * (double)kv[g][c].x;
      acc += (double)qv[c].y * (double)kv[g][c].y;
      acc += (double)qv[c].z * (double)kv[g][c].z;
      acc += (double)qv[c].w * (double)kv[g][c].w;
    }
    acc += __shfl_xor(acc, 1);
    acc += __shfl_xor(acc, 2);      // all 4 j-lanes now hold dot_s
    if (g * 16 + s16 < u) { mv = fmax(mv, acc); sv += acc; }
  }
  for (int off = 4; off < 64; off <<= 1) {
    mv = fmax(mv, __shfl_xor(mv, off));
    sv += __shfl_xor(sv, off);
  }
  if (lane == 0) Mout[(size_t)bh * L + l] = (float)(mv - sv / (double)L);
}

// iterative top-u argmax per (b,h); tie -> smaller index (matches lax.top_k)
__global__ __launch_bounds__(256) void k_topk(const float* __restrict__ M,
    int* __restrict__ top, int L, int u) {
  __shared__ float mv[4096];
  __shared__ float rv[256];
  __shared__ int ri[256];
  int bh = blockIdx.x, t = threadIdx.x;
  const float* Mr = M + (size_t)bh * L;
  for (int k = t; k < L; k += 256) mv[k] = Mr[k];
  __syncthreads();
  for (int it = 0; it < u; it++) {
    float bv = -1e30f; int bi = 0x7fffffff;
    for (int k = t; k < L; k += 256) {
      float v = mv[k];
      if (v > bv) { bv = v; bi = k; }
    }
    rv[t] = bv; ri[t] = bi;
    __syncthreads();
    for (int off = 128; off; off >>= 1) {
      if (t < off) {
        float v2 = rv[t + off]; int i2 = ri[t + off];
        if (v2 > rv[t] || (v2 == rv[t] && i2 < ri[t])) { rv[t] = v2; ri[t] = i2; }
      }
      __syncthreads();
    }
    if (t == 0) { top[bh * u + it] = ri[0]; mv[ri[0]] = -1e30f; }
    __syncthreads();
  }
}

// ATT <- broadcast mean
__global__ void k_fill(float* __restrict__ A, const float* __restrict__ meanq, int L) {
  size_t t = (size_t)blockIdx.x * 256 + threadIdx.x;
  size_t e = t * 4;
  int dm = (int)(e & 511);
  int b = (int)((e >> 9) / (size_t)L);
  *(float4*)(A + e) = *(const float4*)(meanq + b * 512 + dm);
}

// S[bh,ur,k] = scale * dot(q_red[ur], q_k) for 64-k tile per block
__global__ __launch_bounds__(256) void k_scores(const float* __restrict__ X,
    const int* __restrict__ top, float* __restrict__ S, int L, int u) {
  __shared__ __align__(16) float ktT[64][68];
  __shared__ __align__(16) float qred[48][64];
  int bh = blockIdx.y, b = bh >> 3, h = bh & 7;
  int k0 = blockIdx.x * 64;
  int t = threadIdx.x;
  const float* Xbh = X + (size_t)b * L * 512 + h * 64;
#pragma unroll
  for (int it = 0; it < 4; it++) {
    int lin = t + it * 256;                // (kk, fi) over 64x16
    int kk = lin >> 4, fi = lin & 15;
    float4 v = *(const float4*)(Xbh + (size_t)(k0 + kk) * 512 + fi * 4);
    ktT[fi * 4 + 0][kk] = v.x; ktT[fi * 4 + 1][kk] = v.y;
    ktT[fi * 4 + 2][kk] = v.z; ktT[fi * 4 + 3][kk] = v.w;
  }
#pragma unroll
  for (int it = 0; it < 3; it++) {
    int lin = t + it * 256;                // (ur, fi) over 48x16
    int ur = lin >> 4, fi = lin & 15;
    if (ur < u) {
      int row = top[bh * u + ur];
      *(float4*)(&qred[ur][fi * 4]) = *(const float4*)(Xbh + (size_t)row * 512 + fi * 4);
    } else if (ur < 48) {
      *(float4*)(&qred[ur][fi * 4]) = make_float4(0.f, 0.f, 0.f, 0.f);
    }
  }
  __syncthreads();
  int xq = t & 15, y = t >> 4;
  float acc[3][4];
#pragma unroll
  for (int j = 0; j < 3; j++)
#pragma unroll
    for (int e = 0; e < 4; e++) acc[j][e] = 0.f;
  for (int d = 0; d < 64; d++) {
    float4 kv = *(const float4*)(&ktT[d][xq * 4]);
#pragma unroll
    for (int j = 0; j < 3; j++) {
      float qv = qred[y * 3 + j][d];
      acc[j][0] = fmaf(qv, kv.x, acc[j][0]);
      acc[j][1] = fmaf(qv, kv.y, acc[j][1]);
      acc[j][2] = fmaf(qv, kv.z, acc[j][2]);
      acc[j][3] = fmaf(qv, kv.w, acc[j][3]);
    }
  }
#pragma unroll
  for (int j = 0; j < 3; j++) {
    int ur = y * 3 + j;
    if (ur < u) {
      float4 o = make_float4(acc[j][0] * 0.125f, acc[j][1] * 0.125f,
                             acc[j][2] * 0.125f, acc[j][3] * 0.125f);
      *(float4*)(S + ((size_t)(bh * u + ur)) * L + k0 + xq * 4) = o;
    }
  }
}

// softmax over k + ctx_top row, written straight into ATT at top position.
__global__ __launch_bounds__(256) void k_ctx(const float* __restrict__ X,
    const float* __restrict__ S, const int* __restrict__ top,
    float* __restrict__ A, int L, int u) {
  int ur = blockIdx.x, bh = blockIdx.y, b = bh >> 3, h = bh & 7;
  const float* Srow = S + ((size_t)(bh * u + ur)) * L;
  int t = threadIdx.x;
  __shared__ float wtab[4096];
  __shared__ float rm[256];
  __shared__ double rs[256];
  __shared__ double red[4][64];
  float m = -1e30f;
  for (int k = t; k < L; k += 256) m = fmaxf(m, Srow[k]);
  rm[t] = m; __syncthreads();
  for (int off = 128; off; off >>= 1) {
    if (t < off) rm[t] = fmaxf(rm[t], rm[t + off]);
    __syncthreads();
  }
  float mx = rm[0];
  double s = 0.0;
  for (int k = t; k < L; k += 256) { float e = expf(Srow[k] - mx); wtab[k] = e; s += (double)e; }
  rs[t] = s; __syncthreads();
  for (int off = 128; off; off >>= 1) {
    if (t < off) rs[t] += rs[t + off];
    __syncthreads();
  }
  double inv = 1.0 / rs[0];
  int w = t >> 6, lane = t & 63;
  const float* Xc = X + (size_t)b * L * 512 + h * 64 + lane;
  double a0 = 0.0, a1 = 0.0, a2 = 0.0, a3 = 0.0;
  double a4 = 0.0, a5 = 0.0, a6 = 0.0, a7 = 0.0;
  for (int j = w; j < L; j += 32) {
    float x0 = Xc[(size_t)j * 512];
    float x1 = Xc[(size_t)(j + 4) * 512];
    float x2 = Xc[(size_t)(j + 8) * 512];
    float x3 = Xc[(size_t)(j + 12) * 512];
    float x4 = Xc[(size_t)(j + 16) * 512];
    float x5 = Xc[(size_t)(j + 20) * 512];
    float x6 = Xc[(size_t)(j + 24) * 512];
    float x7 = Xc[(size_t)(j + 28) * 512];
    float p0 = wtab[j],      p1 = wtab[j + 4],  p2 = wtab[j + 8],  p3 = wtab[j + 12];
    float p4 = wtab[j + 16], p5 = wtab[j + 20], p6 = wtab[j + 24], p7 = wtab[j + 28];
    a0 += (double)p0 * (double)x0; a1 += (double)p1 * (double)x1;
    a2 += (double)p2 * (double)x2; a3 += (double)p3 * (double)x3;
    a4 += (double)p4 * (double)x4; a5 += (double)p5 * (double)x5;
    a6 += (double)p6 * (double)x6; a7 += (double)p7 * (double)x7;
  }
  red[w][lane] = ((a0 + a1) + (a2 + a3)) + ((a4 + a5) + (a6 + a7));
  __syncthreads();
  if (w == 0) {
    double tot = (red[0][lane] + red[1][lane] + red[2][lane] + red[3][lane]) * inv;
    int row = top[bh * u + ur];
    A[((size_t)b * L + row) * 512 + h * 64 + lane] = (float)tot;
  }
}

// X <- LN(X + A) * gs + gb, in place; one wave per 512-wide row
__global__ __launch_bounds__(256) void k_ln1(float* __restrict__ X,
    const float* __restrict__ A, const float* __restrict__ gs,
    const float* __restrict__ gb) {
  int w = threadIdx.x >> 6, lane = threadIdx.x & 63;
  int row = blockIdx.x * 4 + w;
  float* xr = X + (size_t)row * 512;
  const float* ar = A + (size_t)row * 512;
  float v[8]; double s = 0.0, s2 = 0.0;
#pragma unroll
  for (int i = 0; i < 8; i++) {
    float val = xr[lane + i * 64] + ar[lane + i * 64];
    v[i] = val; s += (double)val; s2 += (double)val * (double)val;
  }
  for (int off = 32; off; off >>= 1) { s += __shfl_xor(s, off); s2 += __shfl_xor(s2, off); }
  double mu = s * (1.0 / 512.0);
  double var = s2 * (1.0 / 512.0) - mu * mu;
  float rsd = (float)(1.0 / sqrt(var + 1e-5));
  float muf = (float)mu;
#pragma unroll
  for (int i = 0; i < 8; i++) {
    int d = lane + i * 64;
    xr[d] = (v[i] - muf) * rsd * gs[d] + gb[d];
  }
}

// out <- LN(X + Y2); optional pair-pool (distil); one wave per output row
__global__ __launch_bounds__(256) void k_ln2(const float* __restrict__ X,
    const float* __restrict__ Y2, const float* __restrict__ gs,
    const float* __restrict__ gb, float* __restrict__ out, int pool) {
  int w = threadIdx.x >> 6, lane = threadIdx.x & 63;
  int orow = blockIdx.x * 4 + w;
  float o[8] = {0.f,0.f,0.f,0.f,0.f,0.f,0.f,0.f};
  int reps = pool ? 2 : 1;
  for (int p = 0; p < reps; p++) {
    int row = pool ? (orow * 2 + p) : orow;
    const float* xr = X + (size_t)row * 512;
    const float* yr = Y2 + (size_t)row * 512;
    float v[8]; double s = 0.0, s2 = 0.0;
#pragma unroll
    for (int i = 0; i < 8; i++) {
      float val = xr[lane + i * 64] + yr[lane + i * 64];
      v[i] = val; s += (double)val; s2 += (double)val * (double)val;
    }
    for (int off = 32; off; off >>= 1) { s += __shfl_xor(s, off); s2 += __shfl_xor(s2, off); }
    double mu = s * (1.0 / 512.0);
    double var = s2 * (1.0 / 512.0) - mu * mu;
    float rsd = (float)(1.0 / sqrt(var + 1e-5));
    float muf = (float)mu;
#pragma unroll
    for (int i = 0; i < 8; i++)
      o[i] += (v[i] - muf) * rsd * gs[lane + i * 64] + gb[lane + i * 64];
  }
  float sc = pool ? 0.5f : 1.0f;
#pragma unroll
  for (int i = 0; i < 8; i++)
    out[(size_t)orow * 512 + lane + i * 64] = o[i] * sc;
}

// ---------------- bf16x3 plane machinery ----------------
// fp32 matrix [M][K] row-major -> 3 bf16 planes (hi/mid/lo) in MFMA
// fragment-tile order: plane[tile16_m][kblock32][lane64][8 bf16], where
// lane = ((k>>3)&3)*16 + (m&15), j = k&7.  Tile = 1024 B contiguous, so
// k_gemm6 stages tiles with global_load_lds (wave-uniform base + lane*16)
// and reads fragments with linear conflict-free ds_read_b128.

__device__ inline unsigned bsplit(float x, float y, float& rx, float& ry) {
  union { __hip_bfloat162 h; unsigned u; } c;
  c.h = __float22bfloat162_rn(make_float2(x, y));
  rx = x - __uint_as_float(c.u << 16);
  ry = y - __uint_as_float(c.u & 0xffff0000u);
  return c.u;
}

__device__ inline void split3u(float4 v0, float4 v1,
                               uint4& H, uint4& M, uint4& L) {
  float r[8], r2[8]; float d0, d1;
  H.x = bsplit(v0.x, v0.y, r[0], r[1]);
  H.y = bsplit(v0.z, v0.w, r[2], r[3]);
  H.z = bsplit(v1.x, v1.y, r[4], r[5]);
  H.w = bsplit(v1.z, v1.w, r[6], r[7]);
  M.x = bsplit(r[0], r[1], r2[0], r2[1]);
  M.y = bsplit(r[2], r[3], r2[2], r2[3]);
  M.z = bsplit(r[4], r[5], r2[4], r2[5]);
  M.w = bsplit(r[6], r[7], r2[6], r2[7]);
  L.x = bsplit(r2[0], r2[1], d0, d1);
  L.y = bsplit(r2[2], r2[3], d0, d1);
  L.z = bsplit(r2[4], r2[5], d0, d1);
  L.w = bsplit(r2[6], r2[7], d0, d1);
}

// split fp32 [M][K] -> 3 planes frag-tile order. total8 = M*K/8.
__global__ void k_splitX(const float* __restrict__ X, char* __restrict__ P,
                         int K, int total8) {
  int f = blockIdx.x * 256 + threadIdx.x;
  if (f >= total8) return;
  int k8 = f % (K >> 3), m = f / (K >> 3);
  int k = k8 * 8;
  const float* src = X + (size_t)m * K + k;
  float4 v0 = *(const float4*)(src);
  float4 v1 = *(const float4*)(src + 4);
  uint4 H, Md, L;
  split3u(v0, v1, H, Md, L);
  size_t psz = (size_t)total8 * 16;   // M*K*2 bytes per plane
  size_t off = ((size_t)(m >> 4) * (K >> 5) + (k >> 5)) * 1024
             + (size_t)(((k >> 3) & 3) * 256 + (m & 15) * 16);
  *(uint4*)(P + off) = H;
  *(uint4*)(P + psz + off) = Md;
  *(uint4*)(P + 2 * psz + off) = L;
}

__device__ __forceinline__ void async16(void* lds, const void* g) {
  __builtin_amdgcn_global_load_lds(
      (const __attribute__((address_space(1))) uint*)g,
      (__attribute__((address_space(3))) uint*)lds, 16, 0, 0);
}

// C = A @ B^T + bias, A/B as bf16x3 frag-order planes. 6-term bf16x3
// (hh, hm, mh, mm, hl, lh) -> fp32-faithful (same order as rounds 4/5).
// Block tile: (MT*16) x 128, BK=32. 4 waves as 2x2. m97-style 2-barrier
// K-loop with global_load_lds width-16 staging.
// PLANES_OUT: epilogue writes gelu output as frag-order planes (FFN1->FFN2).
template <int MT, int GELU, int PLANES_OUT>
__global__ __launch_bounds__(256) void k_gemm6(const char* __restrict__ AP,
    const char* __restrict__ BP, const float* __restrict__ bias,
    void* __restrict__ Cout, int N, int K) {
  __shared__ __align__(16) char lds[(MT + 8) * 3 * 1024];
  const int t = threadIdx.x;
  const int w = t >> 6, lane = t & 63;
  const int bx = blockIdx.x, by = blockIdx.y;
  const int quad = lane >> 4, rit = lane & 15;
  const int Mrows = gridDim.y * (MT * 16);
  const size_t psA = (size_t)Mrows * K * 2;
  const size_t psB = (size_t)N * K * 2;
  const int KB = K >> 5;
  char* ldsA = lds;
  char* ldsB = lds + MT * 3 * 1024;
  const int wm = (w >> 1) * (MT / 2), wn = (w & 1) * 4;
  f32x4 acc[MT / 2][4];
#pragma unroll
  for (int i = 0; i < MT / 2; i++)
#pragma unroll
    for (int j = 0; j < 4; j++) acc[i][j] = (f32x4){0.f, 0.f, 0.f, 0.f};
  for (int kt = 0; kt < KB; kt++) {
    // stage A: MT*3 tiles; B: 24 tiles. issue q = w + 4r round-robin.
#pragma unroll
    for (int r = 0; r < (MT * 3) / 4; r++) {
      int q = w + 4 * r;
      int p = q / MT, tt = q % MT;
      async16(ldsA + (p * MT + tt) * 1024,
              AP + p * psA + ((size_t)(by * MT + tt) * KB + kt) * 1024 + lane * 16);
    }
#pragma unroll
    for (int r = 0; r < 6; r++) {
      int q = w + 4 * r;
      int p = q >> 3, tt = q & 7;
      async16(ldsB + (p * 8 + tt) * 1024,
              BP + p * psB + ((size_t)(bx * 8 + tt) * KB + kt) * 1024 + lane * 16);
    }
    __syncthreads();
    short8 af[3][MT / 2];
#pragma unroll
    for (int p = 0; p < 3; p++)
#pragma unroll
      for (int mi = 0; mi < MT / 2; mi++)
        af[p][mi] = *(const short8*)(ldsA + (p * MT + wm + mi) * 1024 + lane * 16);
#pragma unroll
    for (int ni = 0; ni < 4; ni++) {
      const char* bb = ldsB + (wn + ni) * 1024 + lane * 16;
      short8 bh = *(const short8*)(bb);
      short8 bm = *(const short8*)(bb + 8192);
      short8 bl = *(const short8*)(bb + 16384);
#pragma unroll
      for (int mi = 0; mi < MT / 2; mi++) {
        f32x4 c = acc[mi][ni];
        c = __builtin_amdgcn_mfma_f32_16x16x32_bf16(af[0][mi], bh, c, 0, 0, 0);
        c = __builtin_amdgcn_mfma_f32_16x16x32_bf16(af[0][mi], bm, c, 0, 0, 0);
        c = __builtin_amdgcn_mfma_f32_16x16x32_bf16(af[1][mi], bh, c, 0, 0, 0);
        c = __builtin_amdgcn_mfma_f32_16x16x32_bf16(af[1][mi], bm, c, 0, 0, 0);
        c = __builtin_amdgcn_mfma_f32_16x16x32_bf16(af[0][mi], bl, c, 0, 0, 0);
        c = __builtin_amdgcn_mfma_f32_16x16x32_bf16(af[2][mi], bh, c, 0, 0, 0);
        acc[mi][ni] = c;
      }
    }
    __syncthreads();
  }
  const int n0 = bx * 128, m_base = by * (MT * 16);
  if (!PLANES_OUT) {
    float* C = (float*)Cout;
#pragma unroll
    for (int mi = 0; mi < MT / 2; mi++) {
      const int gr0 = m_base + (wm + mi) * 16 + quad * 4;
#pragma unroll
      for (int ni = 0; ni < 4; ni++) {
        const int gc = n0 + (wn + ni) * 16 + rit;
        const float bia = bias[gc];
#pragma unroll
        for (int e = 0; e < 4; e++) {
          float v = acc[mi][ni][e] + bia;
          if (GELU) v = 0.5f * v * (1.0f + erff(v * 0.7071067811865476f));
          C[(size_t)(gr0 + e) * N + gc] = v;
        }
      }
    }
  } else {
    // write gelu output as frag-order planes (M = Mrows, "K" = N)
    char* CP = (char*)Cout;
    const size_t psC = (size_t)Mrows * N * 2;
    float* lf = (float*)lds;   // 128 x 64 fp32 = 32 KB scratch
    for (int h = 0; h < 2; h++) {
      __syncthreads();
      if ((w & 1) == h) {
#pragma unroll
        for (int ni = 0; ni < 4; ni++) {
          const float bia = bias[n0 + h * 64 + ni * 16 + rit];
#pragma unroll
          for (int mi = 0; mi < MT / 2; mi++) {
            const int ml0 = (wm + mi) * 16 + quad * 4;
#pragma unroll
            for (int e = 0; e < 4; e++) {
              float v = acc[mi][ni][e] + bia;
              if (GELU) v = 0.5f * v * (1.0f + erff(v * 0.7071067811865476f));
              lf[(ml0 + e) * 64 + ni * 16 + rit] = v;
            }
          }
        }
      }
      __syncthreads();
#pragma unroll
      for (int it = 0; it < (MT * 16 * 8) / 256; it++) {
        int p = it * 256 + t;
        int ml = p >> 3, n8 = p & 7;
        float4 v0 = *(const float4*)&lf[ml * 64 + n8 * 8];
        float4 v1 = *(const float4*)&lf[ml * 64 + n8 * 8 + 4];
        uint4 H, Md, L;
        split3u(v0, v1, H, Md, L);
        int mg = m_base + ml, kg = n0 + h * 64 + n8 * 8;
        size_t off = ((size_t)(mg >> 4) * (N >> 5) + (kg >> 5)) * 1024
                   + (size_t)(((kg >> 3) & 3) * 256 + (mg & 15) * 16);
        *(uint4*)(CP + off) = H;
        *(uint4*)(CP + psC + off) = Md;
        *(uint4*)(CP + 2 * psC + off) = L;
      }
    }
  }
}

extern "C" void kernel_launch(void* const* d_in, const int* in_sizes, int n_in,
                              void* d_out, int out_size, void* d_ws, size_t ws_size,
                              hipStream_t stream) {
  const float* x     = (const float*)d_in[0];
  const float* emb_w = (const float*)d_in[1];
  const float* emb_b = (const float*)d_in[2];
  const float* ln1_s = (const float*)d_in[3];
  const float* ln1_b = (const float*)d_in[4];
  const float* w1    = (const float*)d_in[5];
  const float* b1    = (const float*)d_in[6];
  const float* w2    = (const float*)d_in[7];
  const float* b2    = (const float*)d_in[8];
  const float* ln2_s = (const float*)d_in[9];
  const float* ln2_b = (const float*)d_in[10];
  const float* out_w = (const float*)d_in[11];
  const float* out_b = (const float*)d_in[12];
  float* outp = (float*)d_out;

  char* ws = (char*)d_ws;
  if (ws_size < (212ULL << 20)) return;
  float* PE    = (float*)(ws);                    // 8 MiB, dead after embed
  char*  W1S   = ws;                              // 6 MiB planes, overlay PE
  float* BUF[3] = { (float*)(ws + (8ULL << 20)),
                    (float*)(ws + (72ULL << 20)),
                    (float*)(ws + (136ULL << 20)) };  // 3 x 64 MiB
  char*  W2S   = ws + (200ULL << 20);             // 6 MiB planes
  float* MB    = (float*)(ws + (206ULL << 20));   // 1 MiB
  int*   IDX   = (int*)  (ws + (207ULL << 20));
  int*   TOP   = (int*)  (ws + (208ULL << 20));
  float* MEANQ = (float*)(ws + (208ULL << 20) + (64 << 10));
  double* PART = (double*)(ws + (209ULL << 20));  // 1 MiB (64*32*64 fp64)

  k_pe<<<4096 * 512 / 256, 256, 0, stream>>>(PE);
  k_embed<<<(8 * 4096) / 16, 256, 0, stream>>>(x, emb_w, emb_b, PE, BUF[0]);

  const int Ls[3] = {4096, 2048, 1024};
  const int us[3] = {45, 40, 35};
  int xi = 0, ai = 1, yi = 2;
  for (int layer = 0; layer < 3; layer++) {
    const int L = Ls[layer], u = us[layer];
    float* X = BUF[xi]; float* A = BUF[ai]; float* Y = BUF[yi];

    // per-layer weight planes (PE dead after embed)
    k_splitX<<<(2048 * 512 / 8) / 256, 256, 0, stream>>>(
        w1 + (size_t)layer * 2048 * 512, W1S, 512, 2048 * 512 / 8);
    k_splitX<<<(512 * 2048 / 8) / 256, 256, 0, stream>>>(
        w2 + (size_t)layer * 512 * 2048, W2S, 2048, 512 * 2048 / 8);

    unsigned Ka, Kb, k2a, k2b;
    tf2x32(0u, 42u, 0u, (unsigned)layer, Ka, Kb);
    tf2x32(Ka, Kb, 0u, 1u, k2a, k2b);
    const int n = L * u;
    k_idx<<<(n + 255) / 256, 256, 0, stream>>>(IDX, k2a, k2b, n, L - 1);
    const int S = 32;
    k_colmean1<<<dim3(S, 64), 256, 0, stream>>>(X, PART, L, S);
    k_colmean2<<<64, 64, 0, stream>>>(PART, MEANQ, L, S);
    k_M<<<64 * L / 4, 256, 0, stream>>>(X, IDX, MB, L, u);
    k_topk<<<64, 256, 0, stream>>>(MB, TOP, L, u);
    k_fill<<<8 * L / 2, 256, 0, stream>>>(A, MEANQ, L);
    k_scores<<<dim3(L / 64, 64), 256, 0, stream>>>(X, TOP, Y, L, u);
    k_ctx<<<dim3(u, 64), 256, 0, stream>>>(X, Y, TOP, A, L, u);
    k_ln1<<<8 * L / 4, 256, 0, stream>>>(X, A, ln1_s + layer * 512, ln1_b + layer * 512);

    // FFN in 4096-row chunks: YP planes (48 MiB) at Y, XP (12 MiB) at Y+48MiB
    char* YP = (char*)Y;
    char* XP = (char*)Y + (48ULL << 20);
    const int chunks = (8 * L) / 4096;
    for (int c = 0; c < chunks; c++) {
      const float* Xc = X + (size_t)c * 4096 * 512;
      k_splitX<<<(4096 * 512 / 8) / 256, 256, 0, stream>>>(
          Xc, XP, 512, 4096 * 512 / 8);
      k_gemm6<8, 1, 1><<<dim3(16, 32), 256, 0, stream>>>(
          XP, W1S, b1 + layer * 2048, YP, 2048, 512);
      k_gemm6<4, 0, 0><<<dim3(4, 64), 256, 0, stream>>>(
          YP, W2S, b2 + layer * 512, A + (size_t)c * 4096 * 512, 512, 2048);
    }
    if (layer < 2)
      k_ln2<<<8 * (L / 2) / 4, 256, 0, stream>>>(X, A, ln2_s + layer * 512,
                                                 ln2_b + layer * 512, Y, 1);
    else
      k_ln2<<<8 * L / 4, 256, 0, stream>>>(X, A, ln2_s + layer * 512,
                                           ln2_b + layer * 512, Y, 0);
    int tswap = xi; xi = yi; yi = ai; ai = tswap;  // next X = Y
  }
  // final projection: (8192, 512) @ out_w^T + out_b
  char* XFP = (char*)BUF[ai];                      // 24 MiB planes
  char* WOS = W2S;                                 // 1.5 MiB planes
  k_splitX<<<(512 * 512 / 8) / 256, 256, 0, stream>>>(out_w, WOS, 512, 512 * 512 / 8);
  k_splitX<<<(8192 * 512 / 8) / 256, 256, 0, stream>>>(BUF[xi], XFP, 512, 8192 * 512 / 8);
  k_gemm6<8, 0, 0><<<dim3(4, 64), 256, 0, stream>>>(XFP, WOS, out_b, outp, 512, 512);
}